// Round 4
// baseline (1850.125 us; speedup 1.0000x reference)
//
#include <hip/hip_runtime.h>
#include <hip/hip_bf16.h>

constexpr int NB  = 8;
constexpr int NPT = 2048;
constexpr int KK  = 20;
constexpr int PT  = NB * NPT * KK;   // 327680 pixels for layers 1-4
constexpr int BNP = NB * NPT;        // 16384 pixels for layer 5
constexpr float EPS_BN = 1e-5f;

typedef unsigned short u16;          // fp16 storage (ushort punning)

// ---------- workspace layout (bytes), total ~138.5 MiB ----------
constexpr size_t OFF_IDX  = 0;                                   // 16384*20*4
constexpr size_t OFF_WT1  = OFF_IDX + (size_t)BNP * KK * 4;
constexpr size_t OFF_WT2  = OFF_WT1 + 384 * 4;
constexpr size_t OFF_WT3  = OFF_WT2 + 4096 * 4;
constexpr size_t OFF_WT4  = OFF_WT3 + 8192 * 4;
constexpr size_t OFF_WT5  = OFF_WT4 + 32768 * 4;
constexpr size_t OFF_ST   = OFF_WT5 + 262144 * 4;                // 5*1024 f32: sum|sumsq per layer
constexpr size_t OFF_SS   = OFF_ST + 5 * 1024 * 4;               // 5*1024 f32: scale|shift per layer
constexpr size_t OFF_CAT  = OFF_SS + 5 * 1024 * 4;               // fp16 [512][BNP]
constexpr size_t OFF_A    = OFF_CAT + (size_t)512 * BNP * 2;     // fp16, y1 (64ch) then y3 (128ch)
constexpr size_t OFF_B    = OFF_A + (size_t)128 * PT * 2;        // fp16, y2 (64ch)
constexpr size_t WS_NEED  = OFF_B + (size_t)64 * PT * 2;         // 145,188,352 B

__device__ __forceinline__ float h2f(u16 u) {
    _Float16 h; __builtin_memcpy(&h, &u, 2); return (float)h;
}
__device__ __forceinline__ u16 f2h(float f) {
    _Float16 h = (_Float16)f; u16 u; __builtin_memcpy(&u, &h, 2); return u;
}

// ---------- diagnostic: report ws_size via absmax if insufficient ----------
__global__ void marker_kernel(float* __restrict__ out, float v) {
    if (threadIdx.x == 0 && blockIdx.x == 0) out[0] = v;
}

// ---------- W transpose: Wt[c][cout] = W[o][c] ----------
__global__ __launch_bounds__(256) void transpose_w(const float* __restrict__ W,
                                                   float* __restrict__ Wt,
                                                   int cout, int cin) {
    int i = blockIdx.x * 256 + threadIdx.x;
    if (i < cout * cin) {
        int o = i / cin, c = i - o * cin;
        Wt[c * cout + o] = W[i];
    }
}

// ---------- kNN in EXACT (f64) arithmetic: top-20 of neg_dist over 2048 ----------
// f32->f64 promotion is exact; products of f32-valued doubles are exact;
// in-order 3-term f64 sums are bitwise equal to a numpy f64 evaluation.
__global__ __launch_bounds__(256) void knn_kernel(const float* __restrict__ x,
                                                  int* __restrict__ idxo) {
    const int tid = threadIdx.x;
    const int rl  = tid >> 3;            // row within block (0..31)
    const int ch  = tid & 7;             // chunk (0..7)
    const int r   = blockIdx.x * 32 + rl;
    const int b   = r >> 11;
    const int n   = r & 2047;
    const float* xb = x + b * (3 * NPT);

    const double xn0 = (double)xb[n];
    const double xn1 = (double)xb[NPT + n];
    const double xn2 = (double)xb[2 * NPT + n];
    const double sqn = xn0 * xn0 + xn1 * xn1 + xn2 * xn2;

    double bv[KK];
    int    bi[KK];
#pragma unroll
    for (int s = 0; s < KK; ++s) { bv[s] = -1.0e300; bi[s] = 0; }
    double tmin = -1.0e300;

    const int m0 = ch * 256;
    for (int i = 0; i < 256; ++i) {
        int m = m0 + i;
        double xm0 = (double)xb[m];
        double xm1 = (double)xb[NPT + m];
        double xm2 = (double)xb[2 * NPT + m];
        double dot = xn0 * xm0 + xn1 * xm1 + xn2 * xm2;
        double sqm = xm0 * xm0 + xm1 * xm1 + xm2 * xm2;
        double d   = 2.0 * dot - sqn - sqm;
        if (d > tmin) {                     // strict: equal keeps earlier (lower m)
            bool done = false;
#pragma unroll
            for (int s = 0; s < KK; ++s) {
                bool hit = (!done) && (bv[s] == tmin);
                if (hit) { bv[s] = d; bi[s] = m; done = true; }
            }
            tmin = bv[0];
#pragma unroll
            for (int s = 1; s < KK; ++s) tmin = fmin(tmin, bv[s]);
        }
    }

    __shared__ double sv[32][160];          // 40960 B
    __shared__ int    si[32][160];          // 20480 B  (total 61440 < 64K)
#pragma unroll
    for (int s = 0; s < KK; ++s) { sv[rl][ch * KK + s] = bv[s]; si[rl][ch * KK + s] = bi[s]; }
    __syncthreads();

    if (ch == 0) {                          // one merge thread per row
        int* op = idxo + r * KK;
        for (int pass = 0; pass < KK; ++pass) {
            double best = -1.0e308; int bm = 1 << 30; int bs = 0;
            for (int s = 0; s < 160; ++s) {
                double v = sv[rl][s]; int mm = si[rl][s];
                if (v > best || (v == best && mm < bm)) { best = v; bm = mm; bs = s; }
            }
            sv[rl][bs] = -1.7e308;
            op[pass] = bm;
        }
    }
}

// ---------- conv1: edge features on the fly -> y1 [64][PT] fp16 (raw, pre-BN) ----------
__global__ __launch_bounds__(256) void conv1_kernel(const float* __restrict__ x,
                                                    const int* __restrict__ idx,
                                                    const float* __restrict__ Wt,
                                                    u16* __restrict__ y) {
    int p = blockIdx.x * 256 + threadIdx.x;
    int t = p / KK;
    int n = t & 2047;
    int b = t >> 11;
    int m = idx[p];
    const float* xb = x + b * (3 * NPT);
    float f3 = xb[n], f4 = xb[NPT + n], f5 = xb[2 * NPT + n];
    float f0 = xb[m] - f3, f1 = xb[NPT + m] - f4, f2 = xb[2 * NPT + m] - f5;
    float fv[6] = { f0, f1, f2, f3, f4, f5 };

    float acc[64];
#pragma unroll
    for (int o = 0; o < 64; ++o) acc[o] = 0.f;
#pragma unroll
    for (int c = 0; c < 6; ++c) {
        float hv = fv[c];
#pragma unroll
        for (int o = 0; o < 64; ++o) acc[o] = fmaf(Wt[c * 64 + o], hv, acc[o]);
    }
#pragma unroll
    for (int o = 0; o < 64; ++o) y[(size_t)o * PT + p] = f2h(acc[o]);
}

// ---------- conv 2..3: raw y[ob+o][p] = sum_c Wt[c][ob+o] * h[c][p] ----------
template<int CIN>
__global__ __launch_bounds__(256) void conv_mid_kernel(const u16* __restrict__ hin,
                                                       const float* __restrict__ Wt,
                                                       int cout,
                                                       u16* __restrict__ y) {
    int p  = blockIdx.x * 256 + threadIdx.x;
    int ob = blockIdx.y * 64;
    float acc[64];
#pragma unroll
    for (int o = 0; o < 64; ++o) acc[o] = 0.f;
    for (int c = 0; c < CIN; ++c) {
        float hv = h2f(hin[(size_t)c * PT + p]);
        const float* wrow = Wt + c * cout + ob;   // uniform -> s_load
#pragma unroll
        for (int o = 0; o < 64; ++o) acc[o] = fmaf(wrow[o], hv, acc[o]);
    }
#pragma unroll
    for (int o = 0; o < 64; ++o) y[(size_t)(ob + o) * PT + p] = f2h(acc[o]);
}

// ---------- conv4 pass 1: stats only (no y4 store) ----------
__global__ __launch_bounds__(256) void conv4_stats_kernel(const u16* __restrict__ hin,
                                                          const float* __restrict__ Wt,
                                                          float* __restrict__ st) {
    int p  = blockIdx.x * 256 + threadIdx.x;
    int ob = blockIdx.y * 64;
    float acc[64];
#pragma unroll
    for (int o = 0; o < 64; ++o) acc[o] = 0.f;
    for (int c = 0; c < 128; ++c) {
        float hv = h2f(hin[(size_t)c * PT + p]);
        const float* wrow = Wt + c * 256 + ob;
#pragma unroll
        for (int o = 0; o < 64; ++o) acc[o] = fmaf(wrow[o], hv, acc[o]);
    }
    __shared__ float lsum[4][64], lsq[4][64];
    int w = threadIdx.x >> 6, lane = threadIdx.x & 63;
#pragma unroll
    for (int o = 0; o < 64; ++o) {
        float s = acc[o];
        float q = acc[o] * acc[o];
#pragma unroll
        for (int off = 32; off >= 1; off >>= 1) { s += __shfl_down(s, off); q += __shfl_down(q, off); }
        if (lane == 0) { lsum[w][o] = s; lsq[w][o] = q; }
    }
    __syncthreads();
    if (threadIdx.x < 64) {
        int o = threadIdx.x;
        atomicAdd(st + ob + o,       lsum[0][o] + lsum[1][o] + lsum[2][o] + lsum[3][o]);
        atomicAdd(st + 512 + ob + o, lsq[0][o] + lsq[1][o] + lsq[2][o] + lsq[3][o]);
    }
}

// ---------- conv4 pass 2: recompute + BN + ReLU + max over k -> cat (fp16) ----------
__global__ __launch_bounds__(256) void conv4_max_kernel(const u16* __restrict__ hin,
                                                        const float* __restrict__ Wt,
                                                        const float* __restrict__ scsh,
                                                        u16* __restrict__ catp) {
    int t  = blockIdx.x * 256 + threadIdx.x;   // 0..65535
    int kq = t & 3;
    int r  = t >> 2;                           // 0..16383
    int ob = blockIdx.y * 64;
    int p0 = r * KK + kq * 5;

    float mx[64];
#pragma unroll
    for (int o = 0; o < 64; ++o) mx[o] = 0.f;  // post-relu values are >= 0

    for (int px = 0; px < 5; ++px) {
        int p = p0 + px;
        float acc[64];
#pragma unroll
        for (int o = 0; o < 64; ++o) acc[o] = 0.f;
        for (int c = 0; c < 128; ++c) {
            float hv = h2f(hin[(size_t)c * PT + p]);
            const float* wrow = Wt + c * 256 + ob;
#pragma unroll
            for (int o = 0; o < 64; ++o) acc[o] = fmaf(wrow[o], hv, acc[o]);
        }
#pragma unroll
        for (int o = 0; o < 64; ++o) {
            float v = fmaf(acc[o], scsh[ob + o], scsh[512 + ob + o]);   // uniform -> s_load
            mx[o] = fmaxf(mx[o], fmaxf(v, 0.f));
        }
    }
#pragma unroll
    for (int o = 0; o < 64; ++o) {
        float v = mx[o];
        v = fmaxf(v, __shfl_xor(v, 1));
        v = fmaxf(v, __shfl_xor(v, 2));
        if (kq == 0) catp[(size_t)(ob + o) * BNP + r] = f2h(v);
    }
}

// ---------- conv5: cat fp16 [512][BNP] -> out fp32 [b][512][n] (raw, pre-BN) ----------
__global__ __launch_bounds__(256) void conv5_kernel(const u16* __restrict__ cat,
                                                    const float* __restrict__ Wt,
                                                    float* __restrict__ out) {
    int p  = blockIdx.x * 256 + threadIdx.x;     // 0..16383
    int ob = blockIdx.y * 64;
    float acc[64];
#pragma unroll
    for (int o = 0; o < 64; ++o) acc[o] = 0.f;
    for (int c = 0; c < 512; ++c) {
        float hv = h2f(cat[(size_t)c * BNP + p]);
        const float* wrow = Wt + c * 512 + ob;
#pragma unroll
        for (int o = 0; o < 64; ++o) acc[o] = fmaf(wrow[o], hv, acc[o]);
    }
    int b = p >> 11, n = p & 2047;
    float* op = out + ((size_t)(b * 512 + ob)) * 2048 + n;
#pragma unroll
    for (int o = 0; o < 64; ++o) op[(size_t)o * 2048] = acc[o];
}

// ---------- per-channel sum/sumsq over fp16 y [C][PT] ----------
__global__ __launch_bounds__(256) void stats_f16_kernel(const u16* __restrict__ y,
                                                        float* __restrict__ st) {
    int c = blockIdx.y;
    const u16* yc = y + (size_t)c * PT;
    float s = 0.f, q = 0.f;
    int stride = gridDim.x * 1024;
    for (int i0 = blockIdx.x * 1024 + threadIdx.x * 4; i0 < PT; i0 += stride) {
        ushort4 u = *reinterpret_cast<const ushort4*>(yc + i0);
        float v0 = h2f(u.x), v1 = h2f(u.y), v2 = h2f(u.z), v3 = h2f(u.w);
        s += v0 + v1 + v2 + v3;
        q += v0 * v0 + v1 * v1 + v2 * v2 + v3 * v3;
    }
#pragma unroll
    for (int off = 32; off >= 1; off >>= 1) { s += __shfl_down(s, off); q += __shfl_down(q, off); }
    __shared__ float ls[4], lq[4];
    int w = threadIdx.x >> 6, lane = threadIdx.x & 63;
    if (lane == 0) { ls[w] = s; lq[w] = q; }
    __syncthreads();
    if (threadIdx.x == 0) {
        atomicAdd(st + c,       ls[0] + ls[1] + ls[2] + ls[3]);
        atomicAdd(st + 512 + c, lq[0] + lq[1] + lq[2] + lq[3]);
    }
}

// ---------- stats for conv5 output: out layout [b][512][n] ----------
__global__ __launch_bounds__(256) void stats5_kernel(const float* __restrict__ out,
                                                     float* __restrict__ st) {
    int o  = blockIdx.y;
    int n0 = blockIdx.x * 1024 + threadIdx.x * 4;
    float s = 0.f, q = 0.f;
    for (int b = 0; b < NB; ++b) {
        const float* p = out + ((size_t)(b * 512 + o)) * 2048 + n0;
        float4 v = *reinterpret_cast<const float4*>(p);
        s += v.x + v.y + v.z + v.w;
        q += v.x * v.x + v.y * v.y + v.z * v.z + v.w * v.w;
    }
#pragma unroll
    for (int off = 32; off >= 1; off >>= 1) { s += __shfl_down(s, off); q += __shfl_down(q, off); }
    __shared__ float ls[4], lq[4];
    int w = threadIdx.x >> 6, lane = threadIdx.x & 63;
    if (lane == 0) { ls[w] = s; lq[w] = q; }
    __syncthreads();
    if (threadIdx.x == 0) {
        atomicAdd(st + o,       ls[0] + ls[1] + ls[2] + ls[3]);
        atomicAdd(st + 512 + o, lq[0] + lq[1] + lq[2] + lq[3]);
    }
}

// ---------- BN finalize ----------
__global__ void finalize_kernel(const float* __restrict__ st, const float* __restrict__ g,
                                const float* __restrict__ bb, float* __restrict__ scsh,
                                int C, float invM) {
    int c = threadIdx.x;
    if (c < C) {
        float mean = st[c] * invM;
        float var  = st[512 + c] * invM - mean * mean;
        float istd = rsqrtf(var + EPS_BN);
        float sc   = g[c] * istd;
        scsh[c]       = sc;
        scsh[512 + c] = bb[c] - mean * sc;
    }
}

// ---------- normalize + ReLU in place (fp16) + fused max over k -> cat (fp16) ----------
__global__ __launch_bounds__(256) void norm_max_kernel(u16* __restrict__ y,
                                                       const float* __restrict__ scsh,
                                                       u16* __restrict__ catp) {
    int c = blockIdx.y;
    int r = blockIdx.x * 256 + threadIdx.x;     // 0..16383
    float sc = scsh[c], sh = scsh[512 + c];
    u16* yp = y + (size_t)c * PT + r * KK;      // 40B, 8-aligned
    ushort4 u[5];
#pragma unroll
    for (int t = 0; t < 5; ++t) u[t] = reinterpret_cast<const ushort4*>(yp)[t];
    float mx = 0.f;
#pragma unroll
    for (int t = 0; t < 5; ++t) {
        float v0 = fmaxf(fmaf(h2f(u[t].x), sc, sh), 0.f);
        float v1 = fmaxf(fmaf(h2f(u[t].y), sc, sh), 0.f);
        float v2 = fmaxf(fmaf(h2f(u[t].z), sc, sh), 0.f);
        float v3 = fmaxf(fmaf(h2f(u[t].w), sc, sh), 0.f);
        mx = fmaxf(mx, fmaxf(fmaxf(v0, v1), fmaxf(v2, v3)));
        u[t].x = f2h(v0); u[t].y = f2h(v1); u[t].z = f2h(v2); u[t].w = f2h(v3);
    }
#pragma unroll
    for (int t = 0; t < 5; ++t) reinterpret_cast<ushort4*>(yp)[t] = u[t];
    catp[(size_t)c * BNP + r] = f2h(mx);
}

// ---------- final normalize + ReLU on conv5 output in place ----------
__global__ __launch_bounds__(256) void norm5_kernel(float* __restrict__ out,
                                                    const float* __restrict__ scsh) {
    int o = blockIdx.y;
    int r = blockIdx.x * 256 + threadIdx.x;
    int b = r >> 11, n = r & 2047;
    float sc = scsh[o], sh = scsh[512 + o];
    size_t i = ((size_t)(b * 512 + o)) * 2048 + n;
    float v = fmaf(out[i], sc, sh);
    out[i] = v > 0.f ? v : 0.f;
}

extern "C" void kernel_launch(void* const* d_in, const int* in_sizes, int n_in,
                              void* d_out, int out_size, void* d_ws, size_t ws_size,
                              hipStream_t stream) {
    float* out = (float*)d_out;
    if (ws_size < WS_NEED) {
        marker_kernel<<<1, 64, 0, stream>>>(out, 1000.0f + (float)(ws_size >> 20));
        return;
    }

    const float* x  = (const float*)d_in[0];
    const float* W1 = (const float*)d_in[1];
    const float* g1 = (const float*)d_in[2];
    const float* b1 = (const float*)d_in[3];
    const float* W2 = (const float*)d_in[4];
    const float* g2 = (const float*)d_in[5];
    const float* b2 = (const float*)d_in[6];
    const float* W3 = (const float*)d_in[7];
    const float* g3 = (const float*)d_in[8];
    const float* b3 = (const float*)d_in[9];
    const float* W4 = (const float*)d_in[10];
    const float* g4 = (const float*)d_in[11];
    const float* b4 = (const float*)d_in[12];
    const float* W5 = (const float*)d_in[13];
    const float* g5 = (const float*)d_in[14];
    const float* b5 = (const float*)d_in[15];

    char*  ws    = (char*)d_ws;
    int*   idx   = (int*)(ws + OFF_IDX);
    float* wt1   = (float*)(ws + OFF_WT1);
    float* wt2   = (float*)(ws + OFF_WT2);
    float* wt3   = (float*)(ws + OFF_WT3);
    float* wt4   = (float*)(ws + OFF_WT4);
    float* wt5   = (float*)(ws + OFF_WT5);
    float* stats = (float*)(ws + OFF_ST);
    float* scsh  = (float*)(ws + OFF_SS);
    u16*   cat   = (u16*)(ws + OFF_CAT);     // [512][BNP] fp16
    u16*   bufA  = (u16*)(ws + OFF_A);       // y1 (64ch) then y3 (128ch)
    u16*   bufB  = (u16*)(ws + OFF_B);       // y2 (64ch)

    hipMemsetAsync(stats, 0, 5 * 1024 * sizeof(float), stream);

    transpose_w<<<2,    256, 0, stream>>>(W1, wt1, 64, 6);
    transpose_w<<<16,   256, 0, stream>>>(W2, wt2, 64, 64);
    transpose_w<<<32,   256, 0, stream>>>(W3, wt3, 128, 64);
    transpose_w<<<128,  256, 0, stream>>>(W4, wt4, 256, 128);
    transpose_w<<<1024, 256, 0, stream>>>(W5, wt5, 512, 512);

    knn_kernel<<<512, 256, 0, stream>>>(x, idx);

    const float invM  = 1.0f / (float)PT;
    const float invM5 = 1.0f / (float)BNP;

    // L1: 6 -> 64, y1 in bufA
    conv1_kernel<<<PT / 256, 256, 0, stream>>>(x, idx, wt1, bufA);
    stats_f16_kernel<<<dim3(32, 64), 256, 0, stream>>>(bufA, stats + 0);
    finalize_kernel<<<1, 512, 0, stream>>>(stats + 0, g1, b1, scsh + 0, 64, invM);
    norm_max_kernel<<<dim3(BNP / 256, 64), 256, 0, stream>>>(bufA, scsh + 0, cat);

    // L2: 64 -> 64, y2 in bufB
    conv_mid_kernel<64><<<dim3(PT / 256, 1), 256, 0, stream>>>(bufA, wt2, 64, bufB);
    stats_f16_kernel<<<dim3(32, 64), 256, 0, stream>>>(bufB, stats + 1024);
    finalize_kernel<<<1, 512, 0, stream>>>(stats + 1024, g2, b2, scsh + 1024, 64, invM);
    norm_max_kernel<<<dim3(BNP / 256, 64), 256, 0, stream>>>(bufB, scsh + 1024, cat + (size_t)64 * BNP);

    // L3: 64 -> 128, y3 in bufA (y1 dead)
    conv_mid_kernel<64><<<dim3(PT / 256, 2), 256, 0, stream>>>(bufB, wt3, 128, bufA);
    stats_f16_kernel<<<dim3(16, 128), 256, 0, stream>>>(bufA, stats + 2048);
    finalize_kernel<<<1, 512, 0, stream>>>(stats + 2048, g3, b3, scsh + 2048, 128, invM);
    norm_max_kernel<<<dim3(BNP / 256, 128), 256, 0, stream>>>(bufA, scsh + 2048, cat + (size_t)128 * BNP);

    // L4: 128 -> 256, two passes, no y4 storage
    conv4_stats_kernel<<<dim3(PT / 256, 4), 256, 0, stream>>>(bufA, wt4, stats + 3072);
    finalize_kernel<<<1, 512, 0, stream>>>(stats + 3072, g4, b4, scsh + 3072, 256, invM);
    conv4_max_kernel<<<dim3(65536 / 256, 4), 256, 0, stream>>>(bufA, wt4, scsh + 3072,
                                                               cat + (size_t)256 * BNP);

    // L5: 512 -> 512 on cat, output fp32 directly in d_out [b][512][n]
    conv5_kernel<<<dim3(BNP / 256, 8), 256, 0, stream>>>(cat, wt5, out);
    stats5_kernel<<<dim3(2, 512), 256, 0, stream>>>(out, stats + 4096);
    finalize_kernel<<<1, 512, 0, stream>>>(stats + 4096, g5, b5, scsh + 4096, 512, invM5);
    norm5_kernel<<<dim3(BNP / 256, 512), 256, 0, stream>>>(out, scsh + 4096);
}

// Round 5
// 1400.268 us; speedup vs baseline: 1.3213x; 1.3213x over previous
//
#include <hip/hip_runtime.h>
#include <hip/hip_bf16.h>

constexpr int NB  = 8;
constexpr int NPT = 2048;
constexpr int KK  = 20;
constexpr int PT  = NB * NPT * KK;   // 327680 pixels for layers 1-4
constexpr int BNP = NB * NPT;        // 16384 pixels for layer 5
constexpr float EPS_BN = 1e-5f;

typedef unsigned short u16;          // fp16 storage (ushort punning)

// ---------- workspace layout (bytes), total ~138.5 MiB ----------
constexpr size_t OFF_IDX  = 0;                                   // 16384*20*4
constexpr size_t OFF_WT1  = OFF_IDX + (size_t)BNP * KK * 4;
constexpr size_t OFF_WT2  = OFF_WT1 + 384 * 4;
constexpr size_t OFF_WT3  = OFF_WT2 + 4096 * 4;
constexpr size_t OFF_WT4  = OFF_WT3 + 8192 * 4;
constexpr size_t OFF_WT5  = OFF_WT4 + 32768 * 4;
constexpr size_t OFF_ST   = OFF_WT5 + 262144 * 4;                // 5*1024 f32: sum|sumsq per layer
constexpr size_t OFF_SS   = OFF_ST + 5 * 1024 * 4;               // 5*1024 f32: scale|shift per layer
constexpr size_t OFF_CAT  = OFF_SS + 5 * 1024 * 4;               // fp16 [512][BNP]
constexpr size_t OFF_A    = OFF_CAT + (size_t)512 * BNP * 2;     // fp16, y1 (64ch) then y3 (128ch)
constexpr size_t OFF_B    = OFF_A + (size_t)128 * PT * 2;        // fp16, y2 (64ch)
constexpr size_t WS_NEED  = OFF_B + (size_t)64 * PT * 2;         // 145,188,352 B

__device__ __forceinline__ float h2f(u16 u) {
    _Float16 h; __builtin_memcpy(&h, &u, 2); return (float)h;
}
__device__ __forceinline__ u16 f2h(float f) {
    _Float16 h = (_Float16)f; u16 u; __builtin_memcpy(&u, &h, 2); return u;
}

// ---------- diagnostic: report ws_size via absmax if insufficient ----------
__global__ void marker_kernel(float* __restrict__ out, float v) {
    if (threadIdx.x == 0 && blockIdx.x == 0) out[0] = v;
}

// ---------- fused W transposes: Wt[c][cout] = W[o][c], all 5 layers, 1 launch ----------
__global__ __launch_bounds__(256) void transpose_all(
        const float* __restrict__ W1, const float* __restrict__ W2,
        const float* __restrict__ W3, const float* __restrict__ W4,
        const float* __restrict__ W5,
        float* __restrict__ w1, float* __restrict__ w2, float* __restrict__ w3,
        float* __restrict__ w4, float* __restrict__ w5) {
    int i = blockIdx.x * 256 + threadIdx.x;
    // ranges: W1 [0,384) 64x6 | W2 [384,4480) 64x64 | W3 [4480,12672) 128x64
    //         W4 [12672,45440) 256x128 | W5 [45440,307584) 512x512
    if (i < 384) {
        int l = i;          int o = l / 6,   c = l - o * 6;   w1[c * 64  + o] = W1[l];
    } else if (i < 4480) {
        int l = i - 384;    int o = l >> 6,  c = l & 63;      w2[c * 64  + o] = W2[l];
    } else if (i < 12672) {
        int l = i - 4480;   int o = l >> 6,  c = l & 63;      w3[c * 128 + o] = W3[l];
    } else if (i < 45440) {
        int l = i - 12672;  int o = l >> 7,  c = l & 127;     w4[c * 256 + o] = W4[l];
    } else if (i < 307584) {
        int l = i - 45440;  int o = l >> 9,  c = l & 511;     w5[c * 512 + o] = W5[l];
    }
}

// ---------- kNN v2: one wave per row, exact f64, no LDS ----------
// Lane l holds 32 candidates m = i*64+l in registers (f64, exact).
// Selection: 20 rounds of wave argmax via shfl_xor butterfly, (value, -m) lex.
__global__ __launch_bounds__(256) void knn_kernel(const float* __restrict__ x,
                                                  int* __restrict__ idxo) {
    const int lane = threadIdx.x & 63;
    const int wid  = threadIdx.x >> 6;          // 0..3
    const int r    = blockIdx.x * 4 + wid;      // 0..16383
    const int b    = r >> 11;
    const int n    = r & 2047;
    const float* xb = x + b * (3 * NPT);

    const double xn0 = (double)xb[n];
    const double xn1 = (double)xb[NPT + n];
    const double xn2 = (double)xb[2 * NPT + n];
    const double sqn = xn0 * xn0 + xn1 * xn1 + xn2 * xn2;

    double d[32];
#pragma unroll
    for (int i = 0; i < 32; ++i) {
        int m = i * 64 + lane;                  // coalesced: lanes -> consecutive m
        double xm0 = (double)xb[m];
        double xm1 = (double)xb[NPT + m];
        double xm2 = (double)xb[2 * NPT + m];
        double dot = xn0 * xm0 + xn1 * xm1 + xn2 * xm2;
        double sqm = xm0 * xm0 + xm1 * xm1 + xm2 * xm2;
        d[i] = 2.0 * dot - sqn - sqm;
    }

    // lane-local argmax (strict > keeps earliest i = smallest m for this lane)
    double bv = d[0]; int bslot = 0;
#pragma unroll
    for (int i = 1; i < 32; ++i) { if (d[i] > bv) { bv = d[i]; bslot = i; } }
    int bm = bslot * 64 + lane;

    int my_out = 0;
    for (int t = 0; t < KK; ++t) {
        // wave-wide argmax of (value, smaller index wins ties)
        double v = bv; int m = bm;
#pragma unroll
        for (int s = 1; s < 64; s <<= 1) {
            double ov = __shfl_xor(v, s);
            int    om = __shfl_xor(m, s);
            if (ov > v || (ov == v && om < m)) { v = ov; m = om; }
        }
        if (lane == t) my_out = m;              // round t's winner saved by lane t
        if ((m & 63) == lane) {                 // owner: clear slot, rescan local max
            int iw = m >> 6;
            double nb = -1.0e308; int nbi = 0;
#pragma unroll
            for (int i = 0; i < 32; ++i) {
                if (i == iw) d[i] = -1.0e308;
                if (d[i] > nb) { nb = d[i]; nbi = i; }
            }
            bv = nb; bm = nbi * 64 + lane;
        }
    }
    if (lane < KK) idxo[r * KK + lane] = my_out;   // coalesced 20-wide store
}

// ---------- conv1: edge features on the fly -> y1 [64][PT] fp16 (raw, pre-BN) ----------
__global__ __launch_bounds__(256) void conv1_kernel(const float* __restrict__ x,
                                                    const int* __restrict__ idx,
                                                    const float* __restrict__ Wt,
                                                    u16* __restrict__ y) {
    int p = blockIdx.x * 256 + threadIdx.x;
    int t = p / KK;
    int n = t & 2047;
    int b = t >> 11;
    int m = idx[p];
    const float* xb = x + b * (3 * NPT);
    float f3 = xb[n], f4 = xb[NPT + n], f5 = xb[2 * NPT + n];
    float f0 = xb[m] - f3, f1 = xb[NPT + m] - f4, f2 = xb[2 * NPT + m] - f5;
    float fv[6] = { f0, f1, f2, f3, f4, f5 };

    float acc[64];
#pragma unroll
    for (int o = 0; o < 64; ++o) acc[o] = 0.f;
#pragma unroll
    for (int c = 0; c < 6; ++c) {
        float hv = fv[c];
#pragma unroll
        for (int o = 0; o < 64; ++o) acc[o] = fmaf(Wt[c * 64 + o], hv, acc[o]);
    }
#pragma unroll
    for (int o = 0; o < 64; ++o) y[(size_t)o * PT + p] = f2h(acc[o]);
}

// ---------- conv 2..3: raw y[ob+o][p] = sum_c Wt[c][ob+o] * h[c][p] ----------
template<int CIN>
__global__ __launch_bounds__(256) void conv_mid_kernel(const u16* __restrict__ hin,
                                                       const float* __restrict__ Wt,
                                                       int cout,
                                                       u16* __restrict__ y) {
    int p  = blockIdx.x * 256 + threadIdx.x;
    int ob = blockIdx.y * 64;
    float acc[64];
#pragma unroll
    for (int o = 0; o < 64; ++o) acc[o] = 0.f;
    for (int c = 0; c < CIN; ++c) {
        float hv = h2f(hin[(size_t)c * PT + p]);
        const float* wrow = Wt + c * cout + ob;   // uniform -> s_load
#pragma unroll
        for (int o = 0; o < 64; ++o) acc[o] = fmaf(wrow[o], hv, acc[o]);
    }
#pragma unroll
    for (int o = 0; o < 64; ++o) y[(size_t)(ob + o) * PT + p] = f2h(acc[o]);
}

// ---------- conv4 pass 1: stats only (no y4 store) ----------
__global__ __launch_bounds__(256) void conv4_stats_kernel(const u16* __restrict__ hin,
                                                          const float* __restrict__ Wt,
                                                          float* __restrict__ st) {
    int p  = blockIdx.x * 256 + threadIdx.x;
    int ob = blockIdx.y * 64;
    float acc[64];
#pragma unroll
    for (int o = 0; o < 64; ++o) acc[o] = 0.f;
    for (int c = 0; c < 128; ++c) {
        float hv = h2f(hin[(size_t)c * PT + p]);
        const float* wrow = Wt + c * 256 + ob;
#pragma unroll
        for (int o = 0; o < 64; ++o) acc[o] = fmaf(wrow[o], hv, acc[o]);
    }
    __shared__ float lsum[4][64], lsq[4][64];
    int w = threadIdx.x >> 6, lane = threadIdx.x & 63;
#pragma unroll
    for (int o = 0; o < 64; ++o) {
        float s = acc[o];
        float q = acc[o] * acc[o];
#pragma unroll
        for (int off = 32; off >= 1; off >>= 1) { s += __shfl_down(s, off); q += __shfl_down(q, off); }
        if (lane == 0) { lsum[w][o] = s; lsq[w][o] = q; }
    }
    __syncthreads();
    if (threadIdx.x < 64) {
        int o = threadIdx.x;
        atomicAdd(st + ob + o,       lsum[0][o] + lsum[1][o] + lsum[2][o] + lsum[3][o]);
        atomicAdd(st + 512 + ob + o, lsq[0][o] + lsq[1][o] + lsq[2][o] + lsq[3][o]);
    }
}

// ---------- conv4 pass 2: recompute + BN + ReLU + max over k -> cat (fp16) ----------
__global__ __launch_bounds__(256) void conv4_max_kernel(const u16* __restrict__ hin,
                                                        const float* __restrict__ Wt,
                                                        const float* __restrict__ scsh,
                                                        u16* __restrict__ catp) {
    int t  = blockIdx.x * 256 + threadIdx.x;   // 0..65535
    int kq = t & 3;
    int r  = t >> 2;                           // 0..16383
    int ob = blockIdx.y * 64;
    int p0 = r * KK + kq * 5;

    float mx[64];
#pragma unroll
    for (int o = 0; o < 64; ++o) mx[o] = 0.f;  // post-relu values are >= 0

    for (int px = 0; px < 5; ++px) {
        int p = p0 + px;
        float acc[64];
#pragma unroll
        for (int o = 0; o < 64; ++o) acc[o] = 0.f;
        for (int c = 0; c < 128; ++c) {
            float hv = h2f(hin[(size_t)c * PT + p]);
            const float* wrow = Wt + c * 256 + ob;
#pragma unroll
            for (int o = 0; o < 64; ++o) acc[o] = fmaf(wrow[o], hv, acc[o]);
        }
#pragma unroll
        for (int o = 0; o < 64; ++o) {
            float v = fmaf(acc[o], scsh[ob + o], scsh[512 + ob + o]);   // uniform -> s_load
            mx[o] = fmaxf(mx[o], fmaxf(v, 0.f));
        }
    }
#pragma unroll
    for (int o = 0; o < 64; ++o) {
        float v = mx[o];
        v = fmaxf(v, __shfl_xor(v, 1));
        v = fmaxf(v, __shfl_xor(v, 2));
        if (kq == 0) catp[(size_t)(ob + o) * BNP + r] = f2h(v);
    }
}

// ---------- conv5: cat fp16 [512][BNP] -> out fp32 [b][512][n] (raw, pre-BN) ----------
__global__ __launch_bounds__(256) void conv5_kernel(const u16* __restrict__ cat,
                                                    const float* __restrict__ Wt,
                                                    float* __restrict__ out) {
    int p  = blockIdx.x * 256 + threadIdx.x;     // 0..16383
    int ob = blockIdx.y * 64;
    float acc[64];
#pragma unroll
    for (int o = 0; o < 64; ++o) acc[o] = 0.f;
    for (int c = 0; c < 512; ++c) {
        float hv = h2f(cat[(size_t)c * BNP + p]);
        const float* wrow = Wt + c * 512 + ob;
#pragma unroll
        for (int o = 0; o < 64; ++o) acc[o] = fmaf(wrow[o], hv, acc[o]);
    }
    int b = p >> 11, n = p & 2047;
    float* op = out + ((size_t)(b * 512 + ob)) * 2048 + n;
#pragma unroll
    for (int o = 0; o < 64; ++o) op[(size_t)o * 2048] = acc[o];
}

// ---------- per-channel sum/sumsq over fp16 y [C][PT] ----------
__global__ __launch_bounds__(256) void stats_f16_kernel(const u16* __restrict__ y,
                                                        float* __restrict__ st) {
    int c = blockIdx.y;
    const u16* yc = y + (size_t)c * PT;
    float s = 0.f, q = 0.f;
    int stride = gridDim.x * 1024;
    for (int i0 = blockIdx.x * 1024 + threadIdx.x * 4; i0 < PT; i0 += stride) {
        ushort4 u = *reinterpret_cast<const ushort4*>(yc + i0);
        float v0 = h2f(u.x), v1 = h2f(u.y), v2 = h2f(u.z), v3 = h2f(u.w);
        s += v0 + v1 + v2 + v3;
        q += v0 * v0 + v1 * v1 + v2 * v2 + v3 * v3;
    }
#pragma unroll
    for (int off = 32; off >= 1; off >>= 1) { s += __shfl_down(s, off); q += __shfl_down(q, off); }
    __shared__ float ls[4], lq[4];
    int w = threadIdx.x >> 6, lane = threadIdx.x & 63;
    if (lane == 0) { ls[w] = s; lq[w] = q; }
    __syncthreads();
    if (threadIdx.x == 0) {
        atomicAdd(st + c,       ls[0] + ls[1] + ls[2] + ls[3]);
        atomicAdd(st + 512 + c, lq[0] + lq[1] + lq[2] + lq[3]);
    }
}

// ---------- stats for conv5 output: out layout [b][512][n] ----------
__global__ __launch_bounds__(256) void stats5_kernel(const float* __restrict__ out,
                                                     float* __restrict__ st) {
    int o  = blockIdx.y;
    int n0 = blockIdx.x * 1024 + threadIdx.x * 4;
    float s = 0.f, q = 0.f;
    for (int b = 0; b < NB; ++b) {
        const float* p = out + ((size_t)(b * 512 + o)) * 2048 + n0;
        float4 v = *reinterpret_cast<const float4*>(p);
        s += v.x + v.y + v.z + v.w;
        q += v.x * v.x + v.y * v.y + v.z * v.z + v.w * v.w;
    }
#pragma unroll
    for (int off = 32; off >= 1; off >>= 1) { s += __shfl_down(s, off); q += __shfl_down(q, off); }
    __shared__ float ls[4], lq[4];
    int w = threadIdx.x >> 6, lane = threadIdx.x & 63;
    if (lane == 0) { ls[w] = s; lq[w] = q; }
    __syncthreads();
    if (threadIdx.x == 0) {
        atomicAdd(st + o,       ls[0] + ls[1] + ls[2] + ls[3]);
        atomicAdd(st + 512 + o, lq[0] + lq[1] + lq[2] + lq[3]);
    }
}

// ---------- BN finalize ----------
__global__ void finalize_kernel(const float* __restrict__ st, const float* __restrict__ g,
                                const float* __restrict__ bb, float* __restrict__ scsh,
                                int C, float invM) {
    int c = threadIdx.x;
    if (c < C) {
        float mean = st[c] * invM;
        float var  = st[512 + c] * invM - mean * mean;
        float istd = rsqrtf(var + EPS_BN);
        float sc   = g[c] * istd;
        scsh[c]       = sc;
        scsh[512 + c] = bb[c] - mean * sc;
    }
}

// ---------- normalize + ReLU in place (fp16) + fused max over k -> cat (fp16) ----------
__global__ __launch_bounds__(256) void norm_max_kernel(u16* __restrict__ y,
                                                       const float* __restrict__ scsh,
                                                       u16* __restrict__ catp) {
    int c = blockIdx.y;
    int r = blockIdx.x * 256 + threadIdx.x;     // 0..16383
    float sc = scsh[c], sh = scsh[512 + c];
    u16* yp = y + (size_t)c * PT + r * KK;      // 40B, 8-aligned
    ushort4 u[5];
#pragma unroll
    for (int t = 0; t < 5; ++t) u[t] = reinterpret_cast<const ushort4*>(yp)[t];
    float mx = 0.f;
#pragma unroll
    for (int t = 0; t < 5; ++t) {
        float v0 = fmaxf(fmaf(h2f(u[t].x), sc, sh), 0.f);
        float v1 = fmaxf(fmaf(h2f(u[t].y), sc, sh), 0.f);
        float v2 = fmaxf(fmaf(h2f(u[t].z), sc, sh), 0.f);
        float v3 = fmaxf(fmaf(h2f(u[t].w), sc, sh), 0.f);
        mx = fmaxf(mx, fmaxf(fmaxf(v0, v1), fmaxf(v2, v3)));
        u[t].x = f2h(v0); u[t].y = f2h(v1); u[t].z = f2h(v2); u[t].w = f2h(v3);
    }
#pragma unroll
    for (int t = 0; t < 5; ++t) reinterpret_cast<ushort4*>(yp)[t] = u[t];
    catp[(size_t)c * BNP + r] = f2h(mx);
}

// ---------- final normalize + ReLU on conv5 output in place ----------
__global__ __launch_bounds__(256) void norm5_kernel(float* __restrict__ out,
                                                    const float* __restrict__ scsh) {
    int o = blockIdx.y;
    int r = blockIdx.x * 256 + threadIdx.x;
    int b = r >> 11, n = r & 2047;
    float sc = scsh[o], sh = scsh[512 + o];
    size_t i = ((size_t)(b * 512 + o)) * 2048 + n;
    float v = fmaf(out[i], sc, sh);
    out[i] = v > 0.f ? v : 0.f;
}

extern "C" void kernel_launch(void* const* d_in, const int* in_sizes, int n_in,
                              void* d_out, int out_size, void* d_ws, size_t ws_size,
                              hipStream_t stream) {
    float* out = (float*)d_out;
    if (ws_size < WS_NEED) {
        marker_kernel<<<1, 64, 0, stream>>>(out, 1000.0f + (float)(ws_size >> 20));
        return;
    }

    const float* x  = (const float*)d_in[0];
    const float* W1 = (const float*)d_in[1];
    const float* g1 = (const float*)d_in[2];
    const float* b1 = (const float*)d_in[3];
    const float* W2 = (const float*)d_in[4];
    const float* g2 = (const float*)d_in[5];
    const float* b2 = (const float*)d_in[6];
    const float* W3 = (const float*)d_in[7];
    const float* g3 = (const float*)d_in[8];
    const float* b3 = (const float*)d_in[9];
    const float* W4 = (const float*)d_in[10];
    const float* g4 = (const float*)d_in[11];
    const float* b4 = (const float*)d_in[12];
    const float* W5 = (const float*)d_in[13];
    const float* g5 = (const float*)d_in[14];
    const float* b5 = (const float*)d_in[15];

    char*  ws    = (char*)d_ws;
    int*   idx   = (int*)(ws + OFF_IDX);
    float* wt1   = (float*)(ws + OFF_WT1);
    float* wt2   = (float*)(ws + OFF_WT2);
    float* wt3   = (float*)(ws + OFF_WT3);
    float* wt4   = (float*)(ws + OFF_WT4);
    float* wt5   = (float*)(ws + OFF_WT5);
    float* stats = (float*)(ws + OFF_ST);
    float* scsh  = (float*)(ws + OFF_SS);
    u16*   cat   = (u16*)(ws + OFF_CAT);     // [512][BNP] fp16
    u16*   bufA  = (u16*)(ws + OFF_A);       // y1 (64ch) then y3 (128ch)
    u16*   bufB  = (u16*)(ws + OFF_B);       // y2 (64ch)

    hipMemsetAsync(stats, 0, 5 * 1024 * sizeof(float), stream);

    transpose_all<<<1202, 256, 0, stream>>>(W1, W2, W3, W4, W5, wt1, wt2, wt3, wt4, wt5);

    knn_kernel<<<4096, 256, 0, stream>>>(x, idx);

    const float invM  = 1.0f / (float)PT;
    const float invM5 = 1.0f / (float)BNP;

    // L1: 6 -> 64, y1 in bufA
    conv1_kernel<<<PT / 256, 256, 0, stream>>>(x, idx, wt1, bufA);
    stats_f16_kernel<<<dim3(32, 64), 256, 0, stream>>>(bufA, stats + 0);
    finalize_kernel<<<1, 512, 0, stream>>>(stats + 0, g1, b1, scsh + 0, 64, invM);
    norm_max_kernel<<<dim3(BNP / 256, 64), 256, 0, stream>>>(bufA, scsh + 0, cat);

    // L2: 64 -> 64, y2 in bufB
    conv_mid_kernel<64><<<dim3(PT / 256, 1), 256, 0, stream>>>(bufA, wt2, 64, bufB);
    stats_f16_kernel<<<dim3(32, 64), 256, 0, stream>>>(bufB, stats + 1024);
    finalize_kernel<<<1, 512, 0, stream>>>(stats + 1024, g2, b2, scsh + 1024, 64, invM);
    norm_max_kernel<<<dim3(BNP / 256, 64), 256, 0, stream>>>(bufB, scsh + 1024, cat + (size_t)64 * BNP);

    // L3: 64 -> 128, y3 in bufA (y1 dead)
    conv_mid_kernel<64><<<dim3(PT / 256, 2), 256, 0, stream>>>(bufB, wt3, 128, bufA);
    stats_f16_kernel<<<dim3(16, 128), 256, 0, stream>>>(bufA, stats + 2048);
    finalize_kernel<<<1, 512, 0, stream>>>(stats + 2048, g3, b3, scsh + 2048, 128, invM);
    norm_max_kernel<<<dim3(BNP / 256, 128), 256, 0, stream>>>(bufA, scsh + 2048, cat + (size_t)128 * BNP);

    // L4: 128 -> 256, two passes, no y4 storage
    conv4_stats_kernel<<<dim3(PT / 256, 4), 256, 0, stream>>>(bufA, wt4, stats + 3072);
    finalize_kernel<<<1, 512, 0, stream>>>(stats + 3072, g4, b4, scsh + 3072, 256, invM);
    conv4_max_kernel<<<dim3(65536 / 256, 4), 256, 0, stream>>>(bufA, wt4, scsh + 3072,
                                                               cat + (size_t)256 * BNP);

    // L5: 512 -> 512 on cat, output fp32 directly in d_out [b][512][n]
    conv5_kernel<<<dim3(BNP / 256, 8), 256, 0, stream>>>(cat, wt5, out);
    stats5_kernel<<<dim3(2, 512), 256, 0, stream>>>(out, stats + 4096);
    finalize_kernel<<<1, 512, 0, stream>>>(stats + 4096, g5, b5, scsh + 4096, 512, invM5);
    norm5_kernel<<<dim3(BNP / 256, 512), 256, 0, stream>>>(out, scsh + 4096);
}

// Round 6
// 981.147 us; speedup vs baseline: 1.8857x; 1.4272x over previous
//
#include <hip/hip_runtime.h>
#include <hip/hip_bf16.h>

typedef _Float16 f16;
typedef unsigned short u16;
typedef _Float16 f16x8 __attribute__((ext_vector_type(8)));
typedef _Float16 f16x4 __attribute__((ext_vector_type(4)));
typedef float    f32x4 __attribute__((ext_vector_type(4)));

constexpr int NB  = 8;
constexpr int NPT = 2048;
constexpr int KK  = 20;
constexpr int PT  = NB * NPT * KK;   // 327680 pixels, layers 1-4
constexpr int BNP = NB * NPT;        // 16384 points
constexpr float EPS_BN = 1e-5f;

// ---------- workspace layout (bytes), total ~144.6 MB ----------
constexpr size_t OFF_IDX = 0;                                    // 16384*20*4
constexpr size_t OFF_WT1 = OFF_IDX + (size_t)BNP * KK * 4;       // 384 f32 (transposed [6][64])
constexpr size_t OFF_WH2 = OFF_WT1 + 384 * 4;                    // f16 row-major [64][64]
constexpr size_t OFF_WH3 = OFF_WH2 + 4096 * 2;                   // [128][64]
constexpr size_t OFF_WH4 = OFF_WH3 + 8192 * 2;                   // [256][128]
constexpr size_t OFF_WH5 = OFF_WH4 + 32768 * 2;                  // [512][512]
constexpr size_t OFF_ST  = OFF_WH5 + 262144 * 2;                 // 5*1024 f32 sum|sumsq
constexpr size_t OFF_SS  = OFF_ST + 5 * 1024 * 4;                // 5*1024 f32 scale|shift
constexpr size_t OFF_CAT = OFF_SS + 5 * 1024 * 4;                // f16 [BNP][512]
constexpr size_t OFF_Y3  = OFF_CAT + (size_t)BNP * 512 * 2;      // f16 [PT][128] (84MB region)
constexpr size_t OFF_Y1  = OFF_Y3 + (size_t)PT * 64 * 2;         // y1 aliases upper half of y3 region
constexpr size_t OFF_Y2  = OFF_Y3 + (size_t)PT * 128 * 2;        // f16 [PT][64]
constexpr size_t WS_NEED = OFF_Y2 + (size_t)PT * 64 * 2;         // 144,573,952 B

// ---------- diagnostic ----------
__global__ void marker_kernel(float* __restrict__ out, float v) {
    if (threadIdx.x == 0 && blockIdx.x == 0) out[0] = v;
}

// ---------- weight prep: W1 -> fp32 transposed [6][64]; W2..5 -> fp16 row-major ----------
__global__ __launch_bounds__(256) void prep_weights(
        const float* __restrict__ W1, const float* __restrict__ W2,
        const float* __restrict__ W3, const float* __restrict__ W4,
        const float* __restrict__ W5,
        float* __restrict__ wt1, f16* __restrict__ wh2, f16* __restrict__ wh3,
        f16* __restrict__ wh4, f16* __restrict__ wh5) {
    int i = blockIdx.x * 256 + threadIdx.x;
    if (i < 384)    { int o = i / 6, c = i - o * 6; wt1[c * 64 + o] = W1[i]; }
    if (i < 4096)   wh2[i] = (f16)W2[i];
    if (i < 8192)   wh3[i] = (f16)W3[i];
    if (i < 32768)  wh4[i] = (f16)W4[i];
    if (i < 262144) wh5[i] = (f16)W5[i];
}

// ---------- kNN: one wave per row, exact f64, no LDS (verified round 5) ----------
__global__ __launch_bounds__(256) void knn_kernel(const float* __restrict__ x,
                                                  int* __restrict__ idxo) {
    const int lane = threadIdx.x & 63;
    const int wid  = threadIdx.x >> 6;
    const int r    = blockIdx.x * 4 + wid;
    const int b    = r >> 11;
    const int n    = r & 2047;
    const float* xb = x + b * (3 * NPT);

    const double xn0 = (double)xb[n];
    const double xn1 = (double)xb[NPT + n];
    const double xn2 = (double)xb[2 * NPT + n];
    const double sqn = xn0 * xn0 + xn1 * xn1 + xn2 * xn2;

    double d[32];
#pragma unroll
    for (int i = 0; i < 32; ++i) {
        int m = i * 64 + lane;
        double xm0 = (double)xb[m];
        double xm1 = (double)xb[NPT + m];
        double xm2 = (double)xb[2 * NPT + m];
        double dot = xn0 * xm0 + xn1 * xm1 + xn2 * xm2;
        double sqm = xm0 * xm0 + xm1 * xm1 + xm2 * xm2;
        d[i] = 2.0 * dot - sqn - sqm;
    }
    double bv = d[0]; int bslot = 0;
#pragma unroll
    for (int i = 1; i < 32; ++i) { if (d[i] > bv) { bv = d[i]; bslot = i; } }
    int bm = bslot * 64 + lane;

    int my_out = 0;
    for (int t = 0; t < KK; ++t) {
        double v = bv; int m = bm;
#pragma unroll
        for (int s = 1; s < 64; s <<= 1) {
            double ov = __shfl_xor(v, s);
            int    om = __shfl_xor(m, s);
            if (ov > v || (ov == v && om < m)) { v = ov; m = om; }
        }
        if (lane == t) my_out = m;
        if ((m & 63) == lane) {
            int iw = m >> 6;
            double nb = -1.0e308; int nbi = 0;
#pragma unroll
            for (int i = 0; i < 32; ++i) {
                if (i == iw) d[i] = -1.0e308;
                if (d[i] > nb) { nb = d[i]; nbi = i; }
            }
            bv = nb; bm = nbi * 64 + lane;
        }
    }
    if (lane < KK) idxo[r * KK + lane] = my_out;
}

// ---------- conv1: edge features -> y1 [P][64] f16 (raw) ----------
__global__ __launch_bounds__(256) void conv1_kernel(const float* __restrict__ x,
                                                    const int* __restrict__ idx,
                                                    const float* __restrict__ Wt,
                                                    f16* __restrict__ y) {
    int p = blockIdx.x * 256 + threadIdx.x;
    int t = p / KK;
    int n = t & 2047;
    int b = t >> 11;
    int m = idx[p];
    const float* xb = x + b * (3 * NPT);
    float f3 = xb[n], f4 = xb[NPT + n], f5 = xb[2 * NPT + n];
    float f0 = xb[m] - f3, f1 = xb[NPT + m] - f4, f2 = xb[2 * NPT + m] - f5;
    float fv[6] = { f0, f1, f2, f3, f4, f5 };

    float acc[64];
#pragma unroll
    for (int o = 0; o < 64; ++o) acc[o] = 0.f;
#pragma unroll
    for (int c = 0; c < 6; ++c) {
        float hv = fv[c];
#pragma unroll
        for (int o = 0; o < 64; ++o) acc[o] = fmaf(Wt[c * 64 + o], hv, acc[o]);
    }
    f16* yp = y + (size_t)p * 64;
#pragma unroll
    for (int o = 0; o < 64; ++o) yp[o] = (f16)acc[o];
}

// ---------- MFMA GEMM core: y[p][ob+o] = sum_c W[ob+o][c] * h[p][c] ----------
// wave tile: 64 px (4 B-tiles) x 64 out (4 A-tiles); A row=lane&15,k=8*(lane>>4)+e;
// B col=lane&15(px),k likewise; D col=lane&15(px), row=4*(lane>>4)+j (out).
template<int CIN, int COUT>
__global__ __launch_bounds__(256) void conv_mfma_kernel(const f16* __restrict__ h,
                                                        const f16* __restrict__ W,
                                                        f16* __restrict__ y) {
    const int lane = threadIdx.x & 63, wid = threadIdx.x >> 6;
    const int lr = lane & 15, lg = lane >> 4;
    const int p0 = blockIdx.x * 256 + wid * 64;
    const int ob = blockIdx.y * 64;

    f32x4 acc[4][4];
#pragma unroll
    for (int pt = 0; pt < 4; ++pt)
#pragma unroll
        for (int t = 0; t < 4; ++t) acc[pt][t] = (f32x4){0.f, 0.f, 0.f, 0.f};

#pragma unroll
    for (int kt = 0; kt < CIN / 32; ++kt) {
        const int koff = kt * 32 + lg * 8;
        f16x8 A[4];
#pragma unroll
        for (int t = 0; t < 4; ++t)
            A[t] = *(const f16x8*)(W + (size_t)(ob + 16 * t + lr) * CIN + koff);
#pragma unroll
        for (int pt = 0; pt < 4; ++pt) {
            f16x8 B = *(const f16x8*)(h + (size_t)(p0 + pt * 16 + lr) * CIN + koff);
#pragma unroll
            for (int t = 0; t < 4; ++t)
                acc[pt][t] = __builtin_amdgcn_mfma_f32_16x16x32_f16(A[t], B, acc[pt][t], 0, 0, 0);
        }
    }
#pragma unroll
    for (int pt = 0; pt < 4; ++pt) {
        int px = p0 + pt * 16 + lr;
#pragma unroll
        for (int t = 0; t < 4; ++t) {
            f16x4 v;
            v[0] = (f16)acc[pt][t][0]; v[1] = (f16)acc[pt][t][1];
            v[2] = (f16)acc[pt][t][2]; v[3] = (f16)acc[pt][t][3];
            *(f16x4*)(y + (size_t)px * COUT + ob + 16 * t + 4 * lg) = v;
        }
    }
}

// ---------- conv4 pass 1: MFMA + in-register stats (no y4 store) ----------
__global__ __launch_bounds__(320) void conv4_stats_mfma(const f16* __restrict__ h,
                                                        const f16* __restrict__ W,
                                                        float* __restrict__ st) {
    const int tid = threadIdx.x, lane = tid & 63, wid = tid >> 6;   // 5 waves
    const int lr = lane & 15, lg = lane >> 4;
    const int p0 = blockIdx.x * 320 + wid * 64;
    const int ob = blockIdx.y * 64;

    f32x4 acc[4][4];
#pragma unroll
    for (int pt = 0; pt < 4; ++pt)
#pragma unroll
        for (int t = 0; t < 4; ++t) acc[pt][t] = (f32x4){0.f, 0.f, 0.f, 0.f};

#pragma unroll
    for (int kt = 0; kt < 4; ++kt) {                 // CIN=128
        const int koff = kt * 32 + lg * 8;
        f16x8 A[4];
#pragma unroll
        for (int t = 0; t < 4; ++t)
            A[t] = *(const f16x8*)(W + (size_t)(ob + 16 * t + lr) * 128 + koff);
#pragma unroll
        for (int pt = 0; pt < 4; ++pt) {
            f16x8 B = *(const f16x8*)(h + (size_t)(p0 + pt * 16 + lr) * 128 + koff);
#pragma unroll
            for (int t = 0; t < 4; ++t)
                acc[pt][t] = __builtin_amdgcn_mfma_f32_16x16x32_f16(A[t], B, acc[pt][t], 0, 0, 0);
        }
    }
    __shared__ float lsum[5][64], lsq[5][64];
#pragma unroll
    for (int t = 0; t < 4; ++t) {
#pragma unroll
        for (int j = 0; j < 4; ++j) {
            float s = acc[0][t][j] + acc[1][t][j] + acc[2][t][j] + acc[3][t][j];
            float q = acc[0][t][j] * acc[0][t][j] + acc[1][t][j] * acc[1][t][j]
                    + acc[2][t][j] * acc[2][t][j] + acc[3][t][j] * acc[3][t][j];
#pragma unroll
            for (int m = 1; m < 16; m <<= 1) { s += __shfl_xor(s, m); q += __shfl_xor(q, m); }
            if (lr == 0) { lsum[wid][16 * t + 4 * lg + j] = s; lsq[wid][16 * t + 4 * lg + j] = q; }
        }
    }
    __syncthreads();
    if (tid < 64) {
        float S = 0.f, Q = 0.f;
#pragma unroll
        for (int w = 0; w < 5; ++w) { S += lsum[w][tid]; Q += lsq[w][tid]; }
        atomicAdd(st + ob + tid, S);
        atomicAdd(st + 512 + ob + tid, Q);
    }
}

// ---------- conv4 pass 2: MFMA + BN + ReLU + max over k -> cat (no y4 store) ----------
__global__ __launch_bounds__(320) void conv4_catmax_mfma(const f16* __restrict__ h,
                                                         const f16* __restrict__ W,
                                                         const float* __restrict__ scsh,
                                                         f16* __restrict__ cat) {
    const int tid = threadIdx.x, lane = tid & 63, wid = tid >> 6;
    const int lr = lane & 15, lg = lane >> 4;
    const int p0 = blockIdx.x * 320 + wid * 64;
    const int ob = blockIdx.y * 64;
    const int r0 = blockIdx.x * 16;                  // 320 px = 16 points exactly

    f32x4 acc[4][4];
#pragma unroll
    for (int pt = 0; pt < 4; ++pt)
#pragma unroll
        for (int t = 0; t < 4; ++t) acc[pt][t] = (f32x4){0.f, 0.f, 0.f, 0.f};

#pragma unroll
    for (int kt = 0; kt < 4; ++kt) {
        const int koff = kt * 32 + lg * 8;
        f16x8 A[4];
#pragma unroll
        for (int t = 0; t < 4; ++t)
            A[t] = *(const f16x8*)(W + (size_t)(ob + 16 * t + lr) * 128 + koff);
#pragma unroll
        for (int pt = 0; pt < 4; ++pt) {
            f16x8 B = *(const f16x8*)(h + (size_t)(p0 + pt * 16 + lr) * 128 + koff);
#pragma unroll
            for (int t = 0; t < 4; ++t)
                acc[pt][t] = __builtin_amdgcn_mfma_f32_16x16x32_f16(A[t], B, acc[pt][t], 0, 0, 0);
        }
    }
    __shared__ f16 sb[320][68];                      // +4 pad vs 64 to spread banks
#pragma unroll
    for (int t = 0; t < 4; ++t) {
        int och = 16 * t + 4 * lg;
        float sc0 = scsh[ob + och], sc1 = scsh[ob + och + 1], sc2 = scsh[ob + och + 2], sc3 = scsh[ob + och + 3];
        float sh0 = scsh[512 + ob + och], sh1 = scsh[512 + ob + och + 1],
              sh2 = scsh[512 + ob + och + 2], sh3 = scsh[512 + ob + och + 3];
#pragma unroll
        for (int pt = 0; pt < 4; ++pt) {
            int pl = wid * 64 + pt * 16 + lr;
            sb[pl][och + 0] = (f16)fmaxf(fmaf(acc[pt][t][0], sc0, sh0), 0.f);
            sb[pl][och + 1] = (f16)fmaxf(fmaf(acc[pt][t][1], sc1, sh1), 0.f);
            sb[pl][och + 2] = (f16)fmaxf(fmaf(acc[pt][t][2], sc2, sh2), 0.f);
            sb[pl][och + 3] = (f16)fmaxf(fmaf(acc[pt][t][3], sc3, sh3), 0.f);
        }
    }
    __syncthreads();
    if (tid < 256) {
        int rl = tid >> 4, cq = tid & 15;
#pragma unroll
        for (int cb = 0; cb < 4; ++cb) {
            int ch = cb * 16 + cq;
            float mx = 0.f;
#pragma unroll
            for (int k = 0; k < KK; ++k) mx = fmaxf(mx, (float)sb[rl * KK + k][ch]);
            cat[(size_t)(r0 + rl) * 512 + 256 + ob + ch] = (f16)mx;
        }
    }
}

// ---------- conv5: MFMA, cat [BNP][512] -> out fp32 [b][512][n] (raw) ----------
__global__ __launch_bounds__(256) void conv5_mfma(const f16* __restrict__ cat,
                                                  const f16* __restrict__ W,
                                                  float* __restrict__ out) {
    const int lane = threadIdx.x & 63, wid = threadIdx.x >> 6;
    const int lr = lane & 15, lg = lane >> 4;
    const int p0 = blockIdx.x * 256 + wid * 64;
    const int ob = blockIdx.y * 64;

    f32x4 acc[4][4];
#pragma unroll
    for (int pt = 0; pt < 4; ++pt)
#pragma unroll
        for (int t = 0; t < 4; ++t) acc[pt][t] = (f32x4){0.f, 0.f, 0.f, 0.f};

#pragma unroll
    for (int kt = 0; kt < 16; ++kt) {                // CIN=512
        const int koff = kt * 32 + lg * 8;
        f16x8 A[4];
#pragma unroll
        for (int t = 0; t < 4; ++t)
            A[t] = *(const f16x8*)(W + (size_t)(ob + 16 * t + lr) * 512 + koff);
#pragma unroll
        for (int pt = 0; pt < 4; ++pt) {
            f16x8 B = *(const f16x8*)(cat + (size_t)(p0 + pt * 16 + lr) * 512 + koff);
#pragma unroll
            for (int t = 0; t < 4; ++t)
                acc[pt][t] = __builtin_amdgcn_mfma_f32_16x16x32_f16(A[t], B, acc[pt][t], 0, 0, 0);
        }
    }
#pragma unroll
    for (int pt = 0; pt < 4; ++pt) {
        int px = p0 + pt * 16 + lr;
        int b = px >> 11, n = px & 2047;
#pragma unroll
        for (int t = 0; t < 4; ++t) {
#pragma unroll
            for (int j = 0; j < 4; ++j) {
                int o = ob + 16 * t + 4 * lg + j;
                out[((size_t)(b * 512 + o)) * 2048 + n] = acc[pt][t][j];
            }
        }
    }
}

// ---------- per-channel stats over raw y [P][C] ----------
template<int C>
__global__ __launch_bounds__(256) void stats_pm_kernel(const f16* __restrict__ y,
                                                       float* __restrict__ st, int P) {
    const int c   = threadIdx.x & (C - 1);
    const int grp = threadIdx.x / C;
    const int GR  = 256 / C;
    const int CH  = P / gridDim.x;
    const int pend = blockIdx.x * CH + CH;
    float s = 0.f, q = 0.f;
    for (int p = blockIdx.x * CH + grp; p < pend; p += GR) {
        float v = (float)y[(size_t)p * C + c];
        s += v; q += v * v;
    }
    atomicAdd(st + c, s);
    atomicAdd(st + 512 + c, q);
}

// ---------- stats for conv5 output [b][512][n] ----------
__global__ __launch_bounds__(256) void stats5_kernel(const float* __restrict__ out,
                                                     float* __restrict__ st) {
    int o  = blockIdx.y;
    int n0 = blockIdx.x * 1024 + threadIdx.x * 4;
    float s = 0.f, q = 0.f;
    for (int b = 0; b < NB; ++b) {
        const float* p = out + ((size_t)(b * 512 + o)) * 2048 + n0;
        float4 v = *reinterpret_cast<const float4*>(p);
        s += v.x + v.y + v.z + v.w;
        q += v.x * v.x + v.y * v.y + v.z * v.z + v.w * v.w;
    }
#pragma unroll
    for (int off = 32; off >= 1; off >>= 1) { s += __shfl_down(s, off); q += __shfl_down(q, off); }
    __shared__ float ls[4], lq[4];
    int w = threadIdx.x >> 6, lane = threadIdx.x & 63;
    if (lane == 0) { ls[w] = s; lq[w] = q; }
    __syncthreads();
    if (threadIdx.x == 0) {
        atomicAdd(st + o,       ls[0] + ls[1] + ls[2] + ls[3]);
        atomicAdd(st + 512 + o, lq[0] + lq[1] + lq[2] + lq[3]);
    }
}

// ---------- BN finalize ----------
__global__ void finalize_kernel(const float* __restrict__ st, const float* __restrict__ g,
                                const float* __restrict__ bb, float* __restrict__ scsh,
                                int C, float invM) {
    int c = threadIdx.x;
    if (c < C) {
        float mean = st[c] * invM;
        float var  = st[512 + c] * invM - mean * mean;
        float istd = rsqrtf(var + EPS_BN);
        float sc   = g[c] * istd;
        scsh[c]       = sc;
        scsh[512 + c] = bb[c] - mean * sc;
    }
}

// ---------- normalize in place ([P][C]) + per-point max -> cat slice ----------
template<int C>
__global__ __launch_bounds__(256) void norm_catmax_kernel(f16* __restrict__ y,
                                                          const float* __restrict__ scsh,
                                                          f16* __restrict__ cat, int coff) {
    const int c   = threadIdx.x & (C - 1);
    const int grp = threadIdx.x / C;
    const int GR  = 256 / C;
    const int r0  = blockIdx.x * 16;
    const float sc = scsh[c], sh = scsh[512 + c];
    for (int rl = grp; rl < 16; rl += GR) {
        int r = r0 + rl;
        f16* base = y + (size_t)r * KK * C + c;
        float mx = 0.f;
#pragma unroll
        for (int k = 0; k < KK; ++k) {
            float v = fmaxf(fmaf((float)base[(size_t)k * C], sc, sh), 0.f);
            base[(size_t)k * C] = (f16)v;
            mx = fmaxf(mx, v);
        }
        cat[(size_t)r * 512 + coff + c] = (f16)mx;
    }
}

// ---------- final normalize + ReLU on conv5 output in place ----------
__global__ __launch_bounds__(256) void norm5_kernel(float* __restrict__ out,
                                                    const float* __restrict__ scsh) {
    int o = blockIdx.y;
    int r = blockIdx.x * 256 + threadIdx.x;
    int b = r >> 11, n = r & 2047;
    float sc = scsh[o], sh = scsh[512 + o];
    size_t i = ((size_t)(b * 512 + o)) * 2048 + n;
    float v = fmaf(out[i], sc, sh);
    out[i] = v > 0.f ? v : 0.f;
}

extern "C" void kernel_launch(void* const* d_in, const int* in_sizes, int n_in,
                              void* d_out, int out_size, void* d_ws, size_t ws_size,
                              hipStream_t stream) {
    float* out = (float*)d_out;
    if (ws_size < WS_NEED) {
        marker_kernel<<<1, 64, 0, stream>>>(out, 1000.0f + (float)(ws_size >> 20));
        return;
    }

    const float* x  = (const float*)d_in[0];
    const float* W1 = (const float*)d_in[1];
    const float* g1 = (const float*)d_in[2];
    const float* b1 = (const float*)d_in[3];
    const float* W2 = (const float*)d_in[4];
    const float* g2 = (const float*)d_in[5];
    const float* b2 = (const float*)d_in[6];
    const float* W3 = (const float*)d_in[7];
    const float* g3 = (const float*)d_in[8];
    const float* b3 = (const float*)d_in[9];
    const float* W4 = (const float*)d_in[10];
    const float* g4 = (const float*)d_in[11];
    const float* b4 = (const float*)d_in[12];
    const float* W5 = (const float*)d_in[13];
    const float* g5 = (const float*)d_in[14];
    const float* b5 = (const float*)d_in[15];

    char*  ws    = (char*)d_ws;
    int*   idx   = (int*)(ws + OFF_IDX);
    float* wt1   = (float*)(ws + OFF_WT1);
    f16*   wh2   = (f16*)(ws + OFF_WH2);
    f16*   wh3   = (f16*)(ws + OFF_WH3);
    f16*   wh4   = (f16*)(ws + OFF_WH4);
    f16*   wh5   = (f16*)(ws + OFF_WH5);
    float* stats = (float*)(ws + OFF_ST);
    float* scsh  = (float*)(ws + OFF_SS);
    f16*   cat   = (f16*)(ws + OFF_CAT);    // [BNP][512]
    f16*   y1    = (f16*)(ws + OFF_Y1);     // [PT][64]  (upper half of y3 region)
    f16*   y2    = (f16*)(ws + OFF_Y2);     // [PT][64]
    f16*   y3    = (f16*)(ws + OFF_Y3);     // [PT][128] (overwrites y1 when y1 dead)

    hipMemsetAsync(stats, 0, 5 * 1024 * sizeof(float), stream);

    prep_weights<<<1024, 256, 0, stream>>>(W1, W2, W3, W4, W5, wt1, wh2, wh3, wh4, wh5);
    knn_kernel<<<4096, 256, 0, stream>>>(x, idx);

    const float invM  = 1.0f / (float)PT;
    const float invM5 = 1.0f / (float)BNP;

    // L1: 6 -> 64
    conv1_kernel<<<PT / 256, 256, 0, stream>>>(x, idx, wt1, y1);
    stats_pm_kernel<64><<<256, 256, 0, stream>>>(y1, stats + 0, PT);
    finalize_kernel<<<1, 512, 0, stream>>>(stats + 0, g1, b1, scsh + 0, 64, invM);
    norm_catmax_kernel<64><<<BNP / 16, 256, 0, stream>>>(y1, scsh + 0, cat, 0);

    // L2: 64 -> 64 (reads clean h1 = y1)
    conv_mfma_kernel<64, 64><<<dim3(PT / 256, 1), 256, 0, stream>>>(y1, wh2, y2);
    stats_pm_kernel<64><<<256, 256, 0, stream>>>(y2, stats + 1024, PT);
    finalize_kernel<<<1, 512, 0, stream>>>(stats + 1024, g2, b2, scsh + 1024, 64, invM);
    norm_catmax_kernel<64><<<BNP / 16, 256, 0, stream>>>(y2, scsh + 1024, cat, 64);

    // L3: 64 -> 128 (writes y3, clobbers dead y1)
    conv_mfma_kernel<64, 128><<<dim3(PT / 256, 2), 256, 0, stream>>>(y2, wh3, y3);
    stats_pm_kernel<128><<<256, 256, 0, stream>>>(y3, stats + 2048, PT);
    finalize_kernel<<<1, 512, 0, stream>>>(stats + 2048, g3, b3, scsh + 2048, 128, invM);
    norm_catmax_kernel<128><<<BNP / 16, 256, 0, stream>>>(y3, scsh + 2048, cat, 128);

    // L4: 128 -> 256, two MFMA passes, no y4 storage
    conv4_stats_mfma<<<dim3(PT / 320, 4), 320, 0, stream>>>(y3, wh4, stats + 3072);
    finalize_kernel<<<1, 512, 0, stream>>>(stats + 3072, g4, b4, scsh + 3072, 256, invM);
    conv4_catmax_mfma<<<dim3(PT / 320, 4), 320, 0, stream>>>(y3, wh4, scsh + 3072, cat);

    // L5: 512 -> 512 on cat -> d_out raw
    conv5_mfma<<<dim3(BNP / 256, 8), 256, 0, stream>>>(cat, wh5, out);
    stats5_kernel<<<dim3(2, 512), 256, 0, stream>>>(out, stats + 4096);
    finalize_kernel<<<1, 512, 0, stream>>>(stats + 4096, g5, b5, scsh + 4096, 512, invM5);
    norm5_kernel<<<dim3(BNP / 256, 512), 256, 0, stream>>>(out, scsh + 4096);
}

// Round 7
// 690.142 us; speedup vs baseline: 2.6808x; 1.4217x over previous
//
#include <hip/hip_runtime.h>
#include <hip/hip_bf16.h>

typedef _Float16 f16;
typedef _Float16 f16x8 __attribute__((ext_vector_type(8)));
typedef _Float16 f16x4 __attribute__((ext_vector_type(4)));
typedef float    f32x4 __attribute__((ext_vector_type(4)));

constexpr int NB  = 8;
constexpr int NPT = 2048;
constexpr int KK  = 20;
constexpr int PT  = NB * NPT * KK;   // 327680 pixels, layers 1-4
constexpr int BNP = NB * NPT;        // 16384 points
constexpr float EPS_BN = 1e-5f;

// ---------- workspace layout (bytes), total ~144.6 MB ----------
constexpr size_t OFF_IDX = 0;
constexpr size_t OFF_WT1 = OFF_IDX + (size_t)BNP * KK * 4;
constexpr size_t OFF_WH2 = OFF_WT1 + 384 * 4;
constexpr size_t OFF_WH3 = OFF_WH2 + 4096 * 2;
constexpr size_t OFF_WH4 = OFF_WH3 + 8192 * 2;
constexpr size_t OFF_WH5 = OFF_WH4 + 32768 * 2;
constexpr size_t OFF_ST  = OFF_WH5 + 262144 * 2;
constexpr size_t OFF_SS  = OFF_ST + 5 * 1024 * 4;
constexpr size_t OFF_CAT = OFF_SS + 5 * 1024 * 4;                // f16 [BNP][512]
constexpr size_t OFF_Y3  = OFF_CAT + (size_t)BNP * 512 * 2;      // f16 [PT][128]
constexpr size_t OFF_Y1  = OFF_Y3 + (size_t)PT * 64 * 2;         // aliases upper half of y3
constexpr size_t OFF_Y2  = OFF_Y3 + (size_t)PT * 128 * 2;        // f16 [PT][64]
constexpr size_t WS_NEED = OFF_Y2 + (size_t)PT * 64 * 2;         // 144,573,952 B

// ---------- diagnostic ----------
__global__ void marker_kernel(float* __restrict__ out, float v) {
    if (threadIdx.x == 0 && blockIdx.x == 0) out[0] = v;
}

// ---------- weight prep ----------
__global__ __launch_bounds__(256) void prep_weights(
        const float* __restrict__ W1, const float* __restrict__ W2,
        const float* __restrict__ W3, const float* __restrict__ W4,
        const float* __restrict__ W5,
        float* __restrict__ wt1, f16* __restrict__ wh2, f16* __restrict__ wh3,
        f16* __restrict__ wh4, f16* __restrict__ wh5) {
    int i = blockIdx.x * 256 + threadIdx.x;
    if (i < 384)    { int o = i / 6, c = i - o * 6; wt1[c * 64 + o] = W1[i]; }
    if (i < 4096)   wh2[i] = (f16)W2[i];
    if (i < 8192)   wh3[i] = (f16)W3[i];
    if (i < 32768)  wh4[i] = (f16)W4[i];
    if (i < 262144) wh5[i] = (f16)W5[i];
}

// ---------- kNN v3: f32 screen (top-26) + exact f64 refine (top-20) ----------
// One wave per row. Screen: same butterfly/rescan structure as the verified f64
// version, in f32. Refine: recompute the 26 survivors' distances in f64 (same
// expression as the verified kernel) and rank by (value, lower index).
__global__ __launch_bounds__(256) void knn_kernel(const float* __restrict__ x,
                                                  int* __restrict__ idxo) {
    const int lane = threadIdx.x & 63;
    const int wid  = threadIdx.x >> 6;
    const int r    = blockIdx.x * 4 + wid;
    const int b    = r >> 11;
    const int n    = r & 2047;
    const float* xb = x + b * (3 * NPT);

    const float xn0 = xb[n], xn1 = xb[NPT + n], xn2 = xb[2 * NPT + n];
    const float sqn = xn0 * xn0 + xn1 * xn1 + xn2 * xn2;

    float d[32];
#pragma unroll
    for (int i = 0; i < 32; ++i) {
        int m = i * 64 + lane;                       // coalesced
        float xm0 = xb[m], xm1 = xb[NPT + m], xm2 = xb[2 * NPT + m];
        float dot = xn0 * xm0 + xn1 * xm1 + xn2 * xm2;
        float sqm = xm0 * xm0 + xm1 * xm1 + xm2 * xm2;
        d[i] = 2.f * dot - sqn - sqm;
    }

    float bv = d[0]; int bs = 0;
#pragma unroll
    for (int i = 1; i < 32; ++i) { if (d[i] > bv) { bv = d[i]; bs = i; } }
    int bm = bs * 64 + lane;

    constexpr int NCAND = 26;                        // 6 margin over k=20
    int my_m = 0;
    for (int t = 0; t < NCAND; ++t) {
        float v = bv; int m = bm;
#pragma unroll
        for (int s = 1; s < 64; s <<= 1) {           // total order: (value, lower m)
            float ov = __shfl_xor(v, s);
            int   om = __shfl_xor(m, s);
            if (ov > v || (ov == v && om < m)) { v = ov; m = om; }
        }
        if (lane == t) my_m = m;
        if ((m & 63) == lane) {                      // unique owner: clear + rescan
            int iw = m >> 6;
            float nb = -3.3e38f; int nbi = 0;
#pragma unroll
            for (int i = 0; i < 32; ++i) {
                if (i == iw) d[i] = -3.3e38f;
                if (d[i] > nb) { nb = d[i]; nbi = i; }
            }
            bv = nb; bm = nbi * 64 + lane;
        }
    }

    // exact f64 refine (expression identical to the verified f64 kernel)
    const double dxn0 = (double)xn0, dxn1 = (double)xn1, dxn2 = (double)xn2;
    const double dsqn = dxn0 * dxn0 + dxn1 * dxn1 + dxn2 * dxn2;
    const int mm = (lane < NCAND) ? my_m : 0;        // guard OOB for idle lanes
    double xm0 = (double)xb[mm], xm1 = (double)xb[NPT + mm], xm2 = (double)xb[2 * NPT + mm];
    double ddot = dxn0 * xm0 + dxn1 * xm1 + dxn2 * xm2;
    double dsqm = xm0 * xm0 + xm1 * xm1 + xm2 * xm2;
    double dd   = 2.0 * ddot - dsqn - dsqm;

    int rank = 0;
    for (int s = 0; s < NCAND; ++s) {
        double ds = __shfl(dd, s);
        int    ms = __shfl(mm, s);
        if (ds > dd || (ds == dd && ms < mm)) ++rank;
    }
    if (lane < NCAND && rank < KK) idxo[r * KK + rank] = mm;  // descending order
}

// ---------- conv1: edge features -> y1 [P][64] f16 (raw) ----------
__global__ __launch_bounds__(256) void conv1_kernel(const float* __restrict__ x,
                                                    const int* __restrict__ idx,
                                                    const float* __restrict__ Wt,
                                                    f16* __restrict__ y) {
    int p = blockIdx.x * 256 + threadIdx.x;
    int t = p / KK;
    int n = t & 2047;
    int b = t >> 11;
    int m = idx[p];
    const float* xb = x + b * (3 * NPT);
    float f3 = xb[n], f4 = xb[NPT + n], f5 = xb[2 * NPT + n];
    float f0 = xb[m] - f3, f1 = xb[NPT + m] - f4, f2 = xb[2 * NPT + m] - f5;
    float fv[6] = { f0, f1, f2, f3, f4, f5 };

    float acc[64];
#pragma unroll
    for (int o = 0; o < 64; ++o) acc[o] = 0.f;
#pragma unroll
    for (int c = 0; c < 6; ++c) {
        float hv = fv[c];
#pragma unroll
        for (int o = 0; o < 64; ++o) acc[o] = fmaf(Wt[c * 64 + o], hv, acc[o]);
    }
    f16* yp = y + (size_t)p * 64;
#pragma unroll
    for (int o = 0; o < 64; ++o) yp[o] = (f16)acc[o];
}

// ---------- MFMA GEMM + fused per-channel stats ----------
template<int CIN, int COUT>
__global__ __launch_bounds__(256) void conv_mfma_kernel(const f16* __restrict__ h,
                                                        const f16* __restrict__ W,
                                                        f16* __restrict__ y,
                                                        float* __restrict__ st) {
    const int tid = threadIdx.x;
    const int lane = tid & 63, wid = tid >> 6;
    const int lr = lane & 15, lg = lane >> 4;
    const int p0 = blockIdx.x * 256 + wid * 64;
    const int ob = blockIdx.y * 64;

    f32x4 acc[4][4];
#pragma unroll
    for (int pt = 0; pt < 4; ++pt)
#pragma unroll
        for (int t = 0; t < 4; ++t) acc[pt][t] = (f32x4){0.f, 0.f, 0.f, 0.f};

#pragma unroll
    for (int kt = 0; kt < CIN / 32; ++kt) {
        const int koff = kt * 32 + lg * 8;
        f16x8 A[4];
#pragma unroll
        for (int t = 0; t < 4; ++t)
            A[t] = *(const f16x8*)(W + (size_t)(ob + 16 * t + lr) * CIN + koff);
#pragma unroll
        for (int pt = 0; pt < 4; ++pt) {
            f16x8 B = *(const f16x8*)(h + (size_t)(p0 + pt * 16 + lr) * CIN + koff);
#pragma unroll
            for (int t = 0; t < 4; ++t)
                acc[pt][t] = __builtin_amdgcn_mfma_f32_16x16x32_f16(A[t], B, acc[pt][t], 0, 0, 0);
        }
    }
#pragma unroll
    for (int pt = 0; pt < 4; ++pt) {
        int px = p0 + pt * 16 + lr;
#pragma unroll
        for (int t = 0; t < 4; ++t) {
            f16x4 v;
            v[0] = (f16)acc[pt][t][0]; v[1] = (f16)acc[pt][t][1];
            v[2] = (f16)acc[pt][t][2]; v[3] = (f16)acc[pt][t][3];
            *(f16x4*)(y + (size_t)px * COUT + ob + 16 * t + 4 * lg) = v;
        }
    }
    // fused stats: sum over the 16 pixels per lane-group via shfl over lr bits
    __shared__ float lsum[4][64], lsq[4][64];
#pragma unroll
    for (int t = 0; t < 4; ++t)
#pragma unroll
        for (int j = 0; j < 4; ++j) {
            float s = acc[0][t][j] + acc[1][t][j] + acc[2][t][j] + acc[3][t][j];
            float q = acc[0][t][j] * acc[0][t][j] + acc[1][t][j] * acc[1][t][j]
                    + acc[2][t][j] * acc[2][t][j] + acc[3][t][j] * acc[3][t][j];
#pragma unroll
            for (int m2 = 1; m2 < 16; m2 <<= 1) { s += __shfl_xor(s, m2); q += __shfl_xor(q, m2); }
            if (lr == 0) { lsum[wid][16 * t + 4 * lg + j] = s; lsq[wid][16 * t + 4 * lg + j] = q; }
        }
    __syncthreads();
    if (tid < 64) {
        float S = lsum[0][tid] + lsum[1][tid] + lsum[2][tid] + lsum[3][tid];
        float Q = lsq[0][tid] + lsq[1][tid] + lsq[2][tid] + lsq[3][tid];
        atomicAdd(st + ob + tid, S);
        atomicAdd(st + 512 + ob + tid, Q);
    }
}

// ---------- conv4 pass 1: B-fragments once, loop 4 out-blocks, stats only ----------
__global__ __launch_bounds__(256) void conv4_stats_mfma(const f16* __restrict__ h,
                                                        const f16* __restrict__ W,
                                                        float* __restrict__ st) {
    const int tid = threadIdx.x, lane = tid & 63, wid = tid >> 6;
    const int lr = lane & 15, lg = lane >> 4;
    const int p0 = blockIdx.x * 256 + wid * 64;

    f16x8 Bf[4][4];                                  // h read ONCE (64 VGPR)
#pragma unroll
    for (int kt = 0; kt < 4; ++kt)
#pragma unroll
        for (int pt = 0; pt < 4; ++pt)
            Bf[kt][pt] = *(const f16x8*)(h + (size_t)(p0 + pt * 16 + lr) * 128 + kt * 32 + lg * 8);

    __shared__ float lsum[4][256], lsq[4][256];

#pragma unroll 1
    for (int ob4 = 0; ob4 < 4; ++ob4) {
        const int ob = ob4 * 64;
        f32x4 acc[4][4];
#pragma unroll
        for (int pt = 0; pt < 4; ++pt)
#pragma unroll
            for (int t = 0; t < 4; ++t) acc[pt][t] = (f32x4){0.f, 0.f, 0.f, 0.f};
#pragma unroll
        for (int kt = 0; kt < 4; ++kt) {
            const int koff = kt * 32 + lg * 8;
            f16x8 A[4];
#pragma unroll
            for (int t = 0; t < 4; ++t)
                A[t] = *(const f16x8*)(W + (size_t)(ob + 16 * t + lr) * 128 + koff);
#pragma unroll
            for (int pt = 0; pt < 4; ++pt)
#pragma unroll
                for (int t = 0; t < 4; ++t)
                    acc[pt][t] = __builtin_amdgcn_mfma_f32_16x16x32_f16(A[t], Bf[kt][pt], acc[pt][t], 0, 0, 0);
        }
#pragma unroll
        for (int t = 0; t < 4; ++t)
#pragma unroll
            for (int j = 0; j < 4; ++j) {
                float s = acc[0][t][j] + acc[1][t][j] + acc[2][t][j] + acc[3][t][j];
                float q = acc[0][t][j] * acc[0][t][j] + acc[1][t][j] * acc[1][t][j]
                        + acc[2][t][j] * acc[2][t][j] + acc[3][t][j] * acc[3][t][j];
#pragma unroll
                for (int m2 = 1; m2 < 16; m2 <<= 1) { s += __shfl_xor(s, m2); q += __shfl_xor(q, m2); }
                if (lr == 0) { lsum[wid][ob + 16 * t + 4 * lg + j] = s; lsq[wid][ob + 16 * t + 4 * lg + j] = q; }
            }
    }
    __syncthreads();
    {
        float S = lsum[0][tid] + lsum[1][tid] + lsum[2][tid] + lsum[3][tid];
        float Q = lsq[0][tid] + lsq[1][tid] + lsq[2][tid] + lsq[3][tid];
        atomicAdd(st + tid, S);
        atomicAdd(st + 512 + tid, Q);
    }
}

// ---------- conv4 pass 2: B once, loop out-blocks, BN+ReLU+max-over-k -> cat ----------
__global__ __launch_bounds__(320) void conv4_catmax_mfma(const f16* __restrict__ h,
                                                         const f16* __restrict__ W,
                                                         const float* __restrict__ scsh,
                                                         f16* __restrict__ cat) {
    const int tid = threadIdx.x, lane = tid & 63, wid = tid >> 6;   // 5 waves
    const int lr = lane & 15, lg = lane >> 4;
    const int p0 = blockIdx.x * 320 + wid * 64;
    const int r0 = blockIdx.x * 16;                  // 320 px = 16 points

    f16x8 Bf[4][4];
#pragma unroll
    for (int kt = 0; kt < 4; ++kt)
#pragma unroll
        for (int pt = 0; pt < 4; ++pt)
            Bf[kt][pt] = *(const f16x8*)(h + (size_t)(p0 + pt * 16 + lr) * 128 + kt * 32 + lg * 8);

    __shared__ f16 sb[320][68];

#pragma unroll 1
    for (int ob4 = 0; ob4 < 4; ++ob4) {
        const int ob = ob4 * 64;
        f32x4 acc[4][4];
#pragma unroll
        for (int pt = 0; pt < 4; ++pt)
#pragma unroll
            for (int t = 0; t < 4; ++t) acc[pt][t] = (f32x4){0.f, 0.f, 0.f, 0.f};
#pragma unroll
        for (int kt = 0; kt < 4; ++kt) {
            const int koff = kt * 32 + lg * 8;
            f16x8 A[4];
#pragma unroll
            for (int t = 0; t < 4; ++t)
                A[t] = *(const f16x8*)(W + (size_t)(ob + 16 * t + lr) * 128 + koff);
#pragma unroll
            for (int pt = 0; pt < 4; ++pt)
#pragma unroll
                for (int t = 0; t < 4; ++t)
                    acc[pt][t] = __builtin_amdgcn_mfma_f32_16x16x32_f16(A[t], Bf[kt][pt], acc[pt][t], 0, 0, 0);
        }
#pragma unroll
        for (int t = 0; t < 4; ++t) {
            int och = 16 * t + 4 * lg;
            float sc0 = scsh[ob + och], sc1 = scsh[ob + och + 1],
                  sc2 = scsh[ob + och + 2], sc3 = scsh[ob + och + 3];
            float sh0 = scsh[512 + ob + och], sh1 = scsh[512 + ob + och + 1],
                  sh2 = scsh[512 + ob + och + 2], sh3 = scsh[512 + ob + och + 3];
#pragma unroll
            for (int pt = 0; pt < 4; ++pt) {
                int pl = wid * 64 + pt * 16 + lr;
                sb[pl][och + 0] = (f16)fmaxf(fmaf(acc[pt][t][0], sc0, sh0), 0.f);
                sb[pl][och + 1] = (f16)fmaxf(fmaf(acc[pt][t][1], sc1, sh1), 0.f);
                sb[pl][och + 2] = (f16)fmaxf(fmaf(acc[pt][t][2], sc2, sh2), 0.f);
                sb[pl][och + 3] = (f16)fmaxf(fmaf(acc[pt][t][3], sc3, sh3), 0.f);
            }
        }
        __syncthreads();
        if (tid < 256) {
            int rl = tid >> 4, cq = tid & 15;
#pragma unroll
            for (int cb = 0; cb < 4; ++cb) {
                int ch = cb * 16 + cq;
                float mx = 0.f;
#pragma unroll
                for (int k = 0; k < KK; ++k) mx = fmaxf(mx, (float)sb[rl * KK + k][ch]);
                cat[(size_t)(r0 + rl) * 512 + 256 + ob + ch] = (f16)mx;
            }
        }
        __syncthreads();
    }
}

// ---------- conv5: MFMA + fused stats, cat [BNP][512] -> out fp32 [b][512][n] ----------
__global__ __launch_bounds__(256) void conv5_mfma(const f16* __restrict__ cat,
                                                  const f16* __restrict__ W,
                                                  float* __restrict__ out,
                                                  float* __restrict__ st) {
    const int tid = threadIdx.x;
    const int lane = tid & 63, wid = tid >> 6;
    const int lr = lane & 15, lg = lane >> 4;
    const int p0 = blockIdx.x * 256 + wid * 64;
    const int ob = blockIdx.y * 64;

    f32x4 acc[4][4];
#pragma unroll
    for (int pt = 0; pt < 4; ++pt)
#pragma unroll
        for (int t = 0; t < 4; ++t) acc[pt][t] = (f32x4){0.f, 0.f, 0.f, 0.f};

#pragma unroll
    for (int kt = 0; kt < 16; ++kt) {
        const int koff = kt * 32 + lg * 8;
        f16x8 A[4];
#pragma unroll
        for (int t = 0; t < 4; ++t)
            A[t] = *(const f16x8*)(W + (size_t)(ob + 16 * t + lr) * 512 + koff);
#pragma unroll
        for (int pt = 0; pt < 4; ++pt) {
            f16x8 B = *(const f16x8*)(cat + (size_t)(p0 + pt * 16 + lr) * 512 + koff);
#pragma unroll
            for (int t = 0; t < 4; ++t)
                acc[pt][t] = __builtin_amdgcn_mfma_f32_16x16x32_f16(A[t], B, acc[pt][t], 0, 0, 0);
        }
    }
#pragma unroll
    for (int pt = 0; pt < 4; ++pt) {
        int px = p0 + pt * 16 + lr;
        int b = px >> 11, n = px & 2047;
#pragma unroll
        for (int t = 0; t < 4; ++t) {
#pragma unroll
            for (int j = 0; j < 4; ++j) {
                int o = ob + 16 * t + 4 * lg + j;
                out[((size_t)(b * 512 + o)) * 2048 + n] = acc[pt][t][j];
            }
        }
    }
    __shared__ float lsum[4][64], lsq[4][64];
#pragma unroll
    for (int t = 0; t < 4; ++t)
#pragma unroll
        for (int j = 0; j < 4; ++j) {
            float s = acc[0][t][j] + acc[1][t][j] + acc[2][t][j] + acc[3][t][j];
            float q = acc[0][t][j] * acc[0][t][j] + acc[1][t][j] * acc[1][t][j]
                    + acc[2][t][j] * acc[2][t][j] + acc[3][t][j] * acc[3][t][j];
#pragma unroll
            for (int m2 = 1; m2 < 16; m2 <<= 1) { s += __shfl_xor(s, m2); q += __shfl_xor(q, m2); }
            if (lr == 0) { lsum[wid][16 * t + 4 * lg + j] = s; lsq[wid][16 * t + 4 * lg + j] = q; }
        }
    __syncthreads();
    if (tid < 64) {
        float S = lsum[0][tid] + lsum[1][tid] + lsum[2][tid] + lsum[3][tid];
        float Q = lsq[0][tid] + lsq[1][tid] + lsq[2][tid] + lsq[3][tid];
        atomicAdd(st + ob + tid, S);
        atomicAdd(st + 512 + ob + tid, Q);
    }
}

// ---------- per-channel stats over raw y [P][C] (layer 1 only) ----------
template<int C>
__global__ __launch_bounds__(256) void stats_pm_kernel(const f16* __restrict__ y,
                                                       float* __restrict__ st, int P) {
    const int c   = threadIdx.x & (C - 1);
    const int grp = threadIdx.x / C;
    const int GR  = 256 / C;
    const int CH  = P / gridDim.x;
    const int pend = blockIdx.x * CH + CH;
    float s = 0.f, q = 0.f;
    for (int p = blockIdx.x * CH + grp; p < pend; p += GR) {
        float v = (float)y[(size_t)p * C + c];
        s += v; q += v * v;
    }
    atomicAdd(st + c, s);
    atomicAdd(st + 512 + c, q);
}

// ---------- BN finalize ----------
__global__ void finalize_kernel(const float* __restrict__ st, const float* __restrict__ g,
                                const float* __restrict__ bb, float* __restrict__ scsh,
                                int C, float invM) {
    int c = threadIdx.x;
    if (c < C) {
        float mean = st[c] * invM;
        float var  = st[512 + c] * invM - mean * mean;
        float istd = rsqrtf(var + EPS_BN);
        float sc   = g[c] * istd;
        scsh[c]       = sc;
        scsh[512 + c] = bb[c] - mean * sc;
    }
}

// ---------- normalize in place ([P][C]) + per-point max -> cat slice ----------
template<int C>
__global__ __launch_bounds__(256) void norm_catmax_kernel(f16* __restrict__ y,
                                                          const float* __restrict__ scsh,
                                                          f16* __restrict__ cat, int coff) {
    const int c   = threadIdx.x & (C - 1);
    const int grp = threadIdx.x / C;
    const int GR  = 256 / C;
    const int r0  = blockIdx.x * 16;
    const float sc = scsh[c], sh = scsh[512 + c];
    for (int rl = grp; rl < 16; rl += GR) {
        int r = r0 + rl;
        f16* base = y + (size_t)r * KK * C + c;
        float mx = 0.f;
#pragma unroll
        for (int k = 0; k < KK; ++k) {
            float v = fmaxf(fmaf((float)base[(size_t)k * C], sc, sh), 0.f);
            base[(size_t)k * C] = (f16)v;
            mx = fmaxf(mx, v);
        }
        cat[(size_t)r * 512 + coff + c] = (f16)mx;
    }
}

// ---------- final normalize + ReLU on conv5 output in place ----------
__global__ __launch_bounds__(256) void norm5_kernel(float* __restrict__ out,
                                                    const float* __restrict__ scsh) {
    int o = blockIdx.y;
    int r = blockIdx.x * 256 + threadIdx.x;
    int b = r >> 11, n = r & 2047;
    float sc = scsh[o], sh = scsh[512 + o];
    size_t i = ((size_t)(b * 512 + o)) * 2048 + n;
    float v = fmaf(out[i], sc, sh);
    out[i] = v > 0.f ? v : 0.f;
}

extern "C" void kernel_launch(void* const* d_in, const int* in_sizes, int n_in,
                              void* d_out, int out_size, void* d_ws, size_t ws_size,
                              hipStream_t stream) {
    float* out = (float*)d_out;
    if (ws_size < WS_NEED) {
        marker_kernel<<<1, 64, 0, stream>>>(out, 1000.0f + (float)(ws_size >> 20));
        return;
    }

    const float* x  = (const float*)d_in[0];
    const float* W1 = (const float*)d_in[1];
    const float* g1 = (const float*)d_in[2];
    const float* b1 = (const float*)d_in[3];
    const float* W2 = (const float*)d_in[4];
    const float* g2 = (const float*)d_in[5];
    const float* b2 = (const float*)d_in[6];
    const float* W3 = (const float*)d_in[7];
    const float* g3 = (const float*)d_in[8];
    const float* b3 = (const float*)d_in[9];
    const float* W4 = (const float*)d_in[10];
    const float* g4 = (const float*)d_in[11];
    const float* b4 = (const float*)d_in[12];
    const float* W5 = (const float*)d_in[13];
    const float* g5 = (const float*)d_in[14];
    const float* b5 = (const float*)d_in[15];

    char*  ws    = (char*)d_ws;
    int*   idx   = (int*)(ws + OFF_IDX);
    float* wt1   = (float*)(ws + OFF_WT1);
    f16*   wh2   = (f16*)(ws + OFF_WH2);
    f16*   wh3   = (f16*)(ws + OFF_WH3);
    f16*   wh4   = (f16*)(ws + OFF_WH4);
    f16*   wh5   = (f16*)(ws + OFF_WH5);
    float* stats = (float*)(ws + OFF_ST);
    float* scsh  = (float*)(ws + OFF_SS);
    f16*   cat   = (f16*)(ws + OFF_CAT);
    f16*   y1    = (f16*)(ws + OFF_Y1);
    f16*   y2    = (f16*)(ws + OFF_Y2);
    f16*   y3    = (f16*)(ws + OFF_Y3);

    hipMemsetAsync(stats, 0, 5 * 1024 * sizeof(float), stream);

    prep_weights<<<1024, 256, 0, stream>>>(W1, W2, W3, W4, W5, wt1, wh2, wh3, wh4, wh5);
    knn_kernel<<<4096, 256, 0, stream>>>(x, idx);

    const float invM  = 1.0f / (float)PT;
    const float invM5 = 1.0f / (float)BNP;

    // L1: 6 -> 64
    conv1_kernel<<<PT / 256, 256, 0, stream>>>(x, idx, wt1, y1);
    stats_pm_kernel<64><<<256, 256, 0, stream>>>(y1, stats + 0, PT);
    finalize_kernel<<<1, 512, 0, stream>>>(stats + 0, g1, b1, scsh + 0, 64, invM);
    norm_catmax_kernel<64><<<BNP / 16, 256, 0, stream>>>(y1, scsh + 0, cat, 0);

    // L2: 64 -> 64 (stats fused)
    conv_mfma_kernel<64, 64><<<dim3(PT / 256, 1), 256, 0, stream>>>(y1, wh2, y2, stats + 1024);
    finalize_kernel<<<1, 512, 0, stream>>>(stats + 1024, g2, b2, scsh + 1024, 64, invM);
    norm_catmax_kernel<64><<<BNP / 16, 256, 0, stream>>>(y2, scsh + 1024, cat, 64);

    // L3: 64 -> 128 (stats fused; clobbers dead y1)
    conv_mfma_kernel<64, 128><<<dim3(PT / 256, 2), 256, 0, stream>>>(y2, wh3, y3, stats + 2048);
    finalize_kernel<<<1, 512, 0, stream>>>(stats + 2048, g3, b3, scsh + 2048, 128, invM);
    norm_catmax_kernel<128><<<BNP / 16, 256, 0, stream>>>(y3, scsh + 2048, cat, 128);

    // L4: 128 -> 256, two passes, y3 read once each, no y4 storage
    conv4_stats_mfma<<<PT / 256, 256, 0, stream>>>(y3, wh4, stats + 3072);
    finalize_kernel<<<1, 512, 0, stream>>>(stats + 3072, g4, b4, scsh + 3072, 256, invM);
    conv4_catmax_mfma<<<PT / 320, 320, 0, stream>>>(y3, wh4, scsh + 3072, cat);

    // L5: 512 -> 512 on cat -> d_out raw (stats fused)
    conv5_mfma<<<dim3(BNP / 256, 8), 256, 0, stream>>>(cat, wh5, out, stats + 4096);
    finalize_kernel<<<1, 512, 0, stream>>>(stats + 4096, g5, b5, scsh + 4096, 512, invM5);
    norm5_kernel<<<dim3(BNP / 256, 512), 256, 0, stream>>>(out, scsh + 4096);
}

// Round 8
// 644.052 us; speedup vs baseline: 2.8726x; 1.0716x over previous
//
#include <hip/hip_runtime.h>
#include <hip/hip_bf16.h>

typedef _Float16 f16;
typedef _Float16 f16x8 __attribute__((ext_vector_type(8)));
typedef _Float16 f16x4 __attribute__((ext_vector_type(4)));
typedef float    f32x4 __attribute__((ext_vector_type(4)));

constexpr int NB  = 8;
constexpr int NPT = 2048;
constexpr int KK  = 20;
constexpr int PT  = NB * NPT * KK;   // 327680 pixels, layers 1-4
constexpr int BNP = NB * NPT;        // 16384 points
constexpr float EPS_BN = 1e-5f;

// ---------- workspace layout (bytes), total ~144.6 MB ----------
constexpr size_t OFF_IDX = 0;
constexpr size_t OFF_WT1 = OFF_IDX + (size_t)BNP * KK * 4;
constexpr size_t OFF_WH2 = OFF_WT1 + 384 * 4;
constexpr size_t OFF_WH3 = OFF_WH2 + 4096 * 2;
constexpr size_t OFF_WH4 = OFF_WH3 + 8192 * 2;
constexpr size_t OFF_WH5 = OFF_WH4 + 32768 * 2;
constexpr size_t OFF_ST  = OFF_WH5 + 262144 * 2;
constexpr size_t OFF_SS  = OFF_ST + 5 * 1024 * 4;
constexpr size_t OFF_CAT = OFF_SS + 5 * 1024 * 4;                // f16 [BNP][512]
constexpr size_t OFF_Y3  = OFF_CAT + (size_t)BNP * 512 * 2;      // f16 [PT][128]
constexpr size_t OFF_Y1  = OFF_Y3 + (size_t)PT * 64 * 2;         // aliases upper half of y3
constexpr size_t OFF_Y2  = OFF_Y3 + (size_t)PT * 128 * 2;        // f16 [PT][64]; at L4: mx4|mn4
constexpr size_t WS_NEED = OFF_Y2 + (size_t)PT * 64 * 2;         // 144,573,952 B

// ---------- diagnostic ----------
__global__ void marker_kernel(float* __restrict__ out, float v) {
    if (threadIdx.x == 0 && blockIdx.x == 0) out[0] = v;
}

// ---------- weight prep ----------
__global__ __launch_bounds__(256) void prep_weights(
        const float* __restrict__ W1, const float* __restrict__ W2,
        const float* __restrict__ W3, const float* __restrict__ W4,
        const float* __restrict__ W5,
        float* __restrict__ wt1, f16* __restrict__ wh2, f16* __restrict__ wh3,
        f16* __restrict__ wh4, f16* __restrict__ wh5) {
    int i = blockIdx.x * 256 + threadIdx.x;
    if (i < 384)    { int o = i / 6, c = i - o * 6; wt1[c * 64 + o] = W1[i]; }
    if (i < 4096)   wh2[i] = (f16)W2[i];
    if (i < 8192)   wh3[i] = (f16)W3[i];
    if (i < 32768)  wh4[i] = (f16)W4[i];
    if (i < 262144) wh5[i] = (f16)W5[i];
}

// ---------- kNN v4: sorted 4-deep lane queue + spill/rescue, f32 screen, f64 refine ----------
__device__ __forceinline__ float distf(const float* __restrict__ xb, int m,
                                       float xn0, float xn1, float xn2, float sqn) {
    float xm0 = xb[m], xm1 = xb[NPT + m], xm2 = xb[2 * NPT + m];
    float dot = xn0 * xm0 + xn1 * xm1 + xn2 * xm2;
    float sqm = xm0 * xm0 + xm1 * xm1 + xm2 * xm2;
    return 2.f * dot - sqn - sqm;
}

__device__ __forceinline__ void qinsert(float d, int m,
        float& q0, float& q1, float& q2, float& q3,
        int& i0, int& i1, int& i2, int& i3, float& spill) {
    bool c0 = (d > q0) || (d == q0 && m < i0);
    bool c1 = (d > q1) || (d == q1 && m < i1);
    bool c2 = (d > q2) || (d == q2 && m < i2);
    bool c3 = (d > q3) || (d == q3 && m < i3);
    spill = fmaxf(spill, c3 ? q3 : d);               // something always drops if c3
    float t2 = q2; int t2i = i2;
    q3 = c2 ? t2 : (c3 ? d : q3); i3 = c2 ? t2i : (c3 ? m : i3);
    float t1 = q1; int t1i = i1;
    q2 = c1 ? t1 : (c2 ? d : q2); i2 = c1 ? t1i : (c2 ? m : i2);
    float t0 = q0; int t0i = i0;
    q1 = c0 ? t0 : (c1 ? d : q1); i1 = c0 ? t0i : (c1 ? m : i1);
    q0 = c0 ? d  : q0;            i0 = c0 ? m  : i0;
}

__global__ __launch_bounds__(256) void knn_kernel(const float* __restrict__ x,
                                                  int* __restrict__ idxo) {
    const int lane = threadIdx.x & 63;
    const int wid  = threadIdx.x >> 6;
    const int r    = blockIdx.x * 4 + wid;
    const int b    = r >> 11;
    const int n    = r & 2047;
    const float* xb = x + b * (3 * NPT);

    const float xn0 = xb[n], xn1 = xb[NPT + n], xn2 = xb[2 * NPT + n];
    const float sqn = xn0 * xn0 + xn1 * xn1 + xn2 * xn2;

    float q0 = -3.3e38f, q1 = -3.3e38f, q2 = -3.3e38f, q3 = -3.3e38f;
    int   i0 = 1 << 30,  i1 = 1 << 30,  i2 = 1 << 30,  i3 = 1 << 30;
    float spill = -3.3e38f;

#pragma unroll
    for (int i = 0; i < 32; ++i) {
        int m = i * 64 + lane;                       // coalesced
        float d = distf(xb, m, xn0, xn1, xn2, sqn);
        qinsert(d, m, q0, q1, q2, q3, i0, i1, i2, i3, spill);
    }

    constexpr int NCAND = 26;                        // margin 6 over k=20
    int my_m = 0;
    for (int t = 0; t < NCAND; ++t) {
        float v = q0; int m = i0;                    // wave argmax, (value, lower m) lex
#pragma unroll
        for (int s = 1; s < 64; s <<= 1) {
            float ov = __shfl_xor(v, s);
            int   om = __shfl_xor(m, s);
            if (ov > v || (ov == v && om < m)) { v = ov; m = om; }
        }
        if (lane == t) my_m = m;
        bool owner = ((m & 63) == lane);
        if (owner) {                                 // pop: shift queue
            q0 = q1; i0 = i1; q1 = q2; i1 = i2; q2 = q3; i2 = i3;
            q3 = -3.3e38f; i3 = 1 << 30;
            if (!(q0 > spill)) {                     // rescue: rebuild from scratch
                q0 = q1 = q2 = q3 = -3.3e38f;
                i0 = i1 = i2 = i3 = 1 << 30;
                spill = -3.3e38f;
                for (int ii = 0; ii < 32; ++ii) {
                    int mr = ii * 64 + lane;
                    float dr = distf(xb, mr, xn0, xn1, xn2, sqn);
                    bool popped = (dr > v) || (dr == v && mr <= m);  // lex >= last pop
                    if (!popped) qinsert(dr, mr, q0, q1, q2, q3, i0, i1, i2, i3, spill);
                }
            }
        }
    }

    // exact f64 refine (expression identical to the verified f64 kernel)
    const double dxn0 = (double)xn0, dxn1 = (double)xn1, dxn2 = (double)xn2;
    const double dsqn = dxn0 * dxn0 + dxn1 * dxn1 + dxn2 * dxn2;
    const int mm = (lane < NCAND) ? my_m : 0;
    double xm0 = (double)xb[mm], xm1 = (double)xb[NPT + mm], xm2 = (double)xb[2 * NPT + mm];
    double ddot = dxn0 * xm0 + dxn1 * xm1 + dxn2 * xm2;
    double dsqm = xm0 * xm0 + xm1 * xm1 + xm2 * xm2;
    double dd   = 2.0 * ddot - dsqn - dsqm;

    int rank = 0;
    for (int s = 0; s < NCAND; ++s) {
        double ds = __shfl(dd, s);
        int    ms = __shfl(mm, s);
        if (ds > dd || (ds == dd && ms < mm)) ++rank;
    }
    if (lane < NCAND && rank < KK) idxo[r * KK + rank] = mm;
}

// ---------- conv1: edge features -> y1 [P][64] f16 (raw) ----------
__global__ __launch_bounds__(256) void conv1_kernel(const float* __restrict__ x,
                                                    const int* __restrict__ idx,
                                                    const float* __restrict__ Wt,
                                                    f16* __restrict__ y) {
    int p = blockIdx.x * 256 + threadIdx.x;
    int t = p / KK;
    int n = t & 2047;
    int b = t >> 11;
    int m = idx[p];
    const float* xb = x + b * (3 * NPT);
    float f3 = xb[n], f4 = xb[NPT + n], f5 = xb[2 * NPT + n];
    float f0 = xb[m] - f3, f1 = xb[NPT + m] - f4, f2 = xb[2 * NPT + m] - f5;
    float fv[6] = { f0, f1, f2, f3, f4, f5 };

    float acc[64];
#pragma unroll
    for (int o = 0; o < 64; ++o) acc[o] = 0.f;
#pragma unroll
    for (int c = 0; c < 6; ++c) {
        float hv = fv[c];
#pragma unroll
        for (int o = 0; o < 64; ++o) acc[o] = fmaf(Wt[c * 64 + o], hv, acc[o]);
    }
    f16* yp = y + (size_t)p * 64;
#pragma unroll
    for (int o = 0; o < 64; ++o) yp[o] = (f16)acc[o];
}

// ---------- MFMA GEMM + fused per-channel stats (layers 2,3) ----------
template<int CIN, int COUT>
__global__ __launch_bounds__(256) void conv_mfma_kernel(const f16* __restrict__ h,
                                                        const f16* __restrict__ W,
                                                        f16* __restrict__ y,
                                                        float* __restrict__ st) {
    const int tid = threadIdx.x;
    const int lane = tid & 63, wid = tid >> 6;
    const int lr = lane & 15, lg = lane >> 4;
    const int p0 = blockIdx.x * 256 + wid * 64;
    const int ob = blockIdx.y * 64;

    f32x4 acc[4][4];
#pragma unroll
    for (int pt = 0; pt < 4; ++pt)
#pragma unroll
        for (int t = 0; t < 4; ++t) acc[pt][t] = (f32x4){0.f, 0.f, 0.f, 0.f};

#pragma unroll
    for (int kt = 0; kt < CIN / 32; ++kt) {
        const int koff = kt * 32 + lg * 8;
        f16x8 A[4];
#pragma unroll
        for (int t = 0; t < 4; ++t)
            A[t] = *(const f16x8*)(W + (size_t)(ob + 16 * t + lr) * CIN + koff);
#pragma unroll
        for (int pt = 0; pt < 4; ++pt) {
            f16x8 B = *(const f16x8*)(h + (size_t)(p0 + pt * 16 + lr) * CIN + koff);
#pragma unroll
            for (int t = 0; t < 4; ++t)
                acc[pt][t] = __builtin_amdgcn_mfma_f32_16x16x32_f16(A[t], B, acc[pt][t], 0, 0, 0);
        }
    }
#pragma unroll
    for (int pt = 0; pt < 4; ++pt) {
        int px = p0 + pt * 16 + lr;
#pragma unroll
        for (int t = 0; t < 4; ++t) {
            f16x4 v;
            v[0] = (f16)acc[pt][t][0]; v[1] = (f16)acc[pt][t][1];
            v[2] = (f16)acc[pt][t][2]; v[3] = (f16)acc[pt][t][3];
            *(f16x4*)(y + (size_t)px * COUT + ob + 16 * t + 4 * lg) = v;
        }
    }
    __shared__ float lsum[4][64], lsq[4][64];
#pragma unroll
    for (int t = 0; t < 4; ++t)
#pragma unroll
        for (int j = 0; j < 4; ++j) {
            float s = acc[0][t][j] + acc[1][t][j] + acc[2][t][j] + acc[3][t][j];
            float q = acc[0][t][j] * acc[0][t][j] + acc[1][t][j] * acc[1][t][j]
                    + acc[2][t][j] * acc[2][t][j] + acc[3][t][j] * acc[3][t][j];
#pragma unroll
            for (int m2 = 1; m2 < 16; m2 <<= 1) { s += __shfl_xor(s, m2); q += __shfl_xor(q, m2); }
            if (lr == 0) { lsum[wid][16 * t + 4 * lg + j] = s; lsq[wid][16 * t + 4 * lg + j] = q; }
        }
    __syncthreads();
    if (tid < 64) {
        float S = lsum[0][tid] + lsum[1][tid] + lsum[2][tid] + lsum[3][tid];
        float Q = lsq[0][tid] + lsq[1][tid] + lsq[2][tid] + lsq[3][tid];
        atomicAdd(st + ob + tid, S);
        atomicAdd(st + 512 + ob + tid, Q);
    }
}

// ---------- conv4 fused: single GEMM -> stats + per-point raw max/min over k ----------
__global__ __launch_bounds__(320) void conv4_fused_mfma(const f16* __restrict__ h,
                                                        const f16* __restrict__ W,
                                                        float* __restrict__ st,
                                                        f16* __restrict__ mx4,
                                                        f16* __restrict__ mn4) {
    const int tid = threadIdx.x, lane = tid & 63, wid = tid >> 6;   // 5 waves
    const int lr = lane & 15, lg = lane >> 4;
    const int p0 = blockIdx.x * 320 + wid * 64;
    const int r0 = blockIdx.x * 16;                  // 320 px = 16 points

    f16x8 Bf[4][4];                                  // h read ONCE
#pragma unroll
    for (int kt = 0; kt < 4; ++kt)
#pragma unroll
        for (int pt = 0; pt < 4; ++pt)
            Bf[kt][pt] = *(const f16x8*)(h + (size_t)(p0 + pt * 16 + lr) * 128 + kt * 32 + lg * 8);

    __shared__ f16   sb[320][68];
    __shared__ float lsum[5][256], lsq[5][256];

#pragma unroll 1
    for (int ob4 = 0; ob4 < 4; ++ob4) {
        const int ob = ob4 * 64;
        f32x4 acc[4][4];
#pragma unroll
        for (int pt = 0; pt < 4; ++pt)
#pragma unroll
            for (int t = 0; t < 4; ++t) acc[pt][t] = (f32x4){0.f, 0.f, 0.f, 0.f};
#pragma unroll
        for (int kt = 0; kt < 4; ++kt) {
            const int koff = kt * 32 + lg * 8;
            f16x8 A[4];
#pragma unroll
            for (int t = 0; t < 4; ++t)
                A[t] = *(const f16x8*)(W + (size_t)(ob + 16 * t + lr) * 128 + koff);
#pragma unroll
            for (int pt = 0; pt < 4; ++pt)
#pragma unroll
                for (int t = 0; t < 4; ++t)
                    acc[pt][t] = __builtin_amdgcn_mfma_f32_16x16x32_f16(A[t], Bf[kt][pt], acc[pt][t], 0, 0, 0);
        }
        // stats
#pragma unroll
        for (int t = 0; t < 4; ++t)
#pragma unroll
            for (int j = 0; j < 4; ++j) {
                float s = acc[0][t][j] + acc[1][t][j] + acc[2][t][j] + acc[3][t][j];
                float q = acc[0][t][j] * acc[0][t][j] + acc[1][t][j] * acc[1][t][j]
                        + acc[2][t][j] * acc[2][t][j] + acc[3][t][j] * acc[3][t][j];
#pragma unroll
                for (int m2 = 1; m2 < 16; m2 <<= 1) { s += __shfl_xor(s, m2); q += __shfl_xor(q, m2); }
                if (lr == 0) { lsum[wid][ob + 16 * t + 4 * lg + j] = s; lsq[wid][ob + 16 * t + 4 * lg + j] = q; }
            }
        // stage raw values, reduce max AND min over k in one LDS pass
#pragma unroll
        for (int t = 0; t < 4; ++t) {
            int och = 16 * t + 4 * lg;
#pragma unroll
            for (int pt = 0; pt < 4; ++pt) {
                int pl = wid * 64 + pt * 16 + lr;
                sb[pl][och + 0] = (f16)acc[pt][t][0];
                sb[pl][och + 1] = (f16)acc[pt][t][1];
                sb[pl][och + 2] = (f16)acc[pt][t][2];
                sb[pl][och + 3] = (f16)acc[pt][t][3];
            }
        }
        __syncthreads();
        if (tid < 256) {
            int rl = tid >> 4, cq = tid & 15;
#pragma unroll
            for (int cb = 0; cb < 4; ++cb) {
                int ch = cb * 16 + cq;
                float mx = -3.3e38f, mn = 3.3e38f;
#pragma unroll
                for (int k = 0; k < KK; ++k) {
                    float v = (float)sb[rl * KK + k][ch];
                    mx = fmaxf(mx, v); mn = fminf(mn, v);
                }
                mx4[(size_t)(r0 + rl) * 256 + ob + ch] = (f16)mx;
                mn4[(size_t)(r0 + rl) * 256 + ob + ch] = (f16)mn;
            }
        }
        __syncthreads();
    }
    if (tid < 256) {
        float S = lsum[0][tid] + lsum[1][tid] + lsum[2][tid] + lsum[3][tid] + lsum[4][tid];
        float Q = lsq[0][tid] + lsq[1][tid] + lsq[2][tid] + lsq[3][tid] + lsq[4][tid];
        atomicAdd(st + tid, S);
        atomicAdd(st + 512 + tid, Q);
    }
}

// ---------- conv4 epilogue: BN+ReLU on max/min (monotone commute) -> cat ----------
__global__ __launch_bounds__(256) void cat4_kernel(const f16* __restrict__ mx4,
                                                   const f16* __restrict__ mn4,
                                                   const float* __restrict__ scsh,
                                                   f16* __restrict__ cat) {
    int i = blockIdx.x * 256 + threadIdx.x;          // 0 .. BNP*256-1
    int r = i >> 8, ch = i & 255;
    float sc = scsh[ch], sh = scsh[512 + ch];
    float v  = (sc > 0.f) ? (float)mx4[i] : (float)mn4[i];
    cat[(size_t)r * 512 + 256 + ch] = (f16)fmaxf(fmaf(v, sc, sh), 0.f);
}

// ---------- conv5: MFMA + fused stats, cat [BNP][512] -> out fp32 [b][512][n] ----------
__global__ __launch_bounds__(256) void conv5_mfma(const f16* __restrict__ cat,
                                                  const f16* __restrict__ W,
                                                  float* __restrict__ out,
                                                  float* __restrict__ st) {
    const int tid = threadIdx.x;
    const int lane = tid & 63, wid = tid >> 6;
    const int lr = lane & 15, lg = lane >> 4;
    const int p0 = blockIdx.x * 256 + wid * 64;
    const int ob = blockIdx.y * 64;

    f32x4 acc[4][4];
#pragma unroll
    for (int pt = 0; pt < 4; ++pt)
#pragma unroll
        for (int t = 0; t < 4; ++t) acc[pt][t] = (f32x4){0.f, 0.f, 0.f, 0.f};

#pragma unroll
    for (int kt = 0; kt < 16; ++kt) {
        const int koff = kt * 32 + lg * 8;
        f16x8 A[4];
#pragma unroll
        for (int t = 0; t < 4; ++t)
            A[t] = *(const f16x8*)(W + (size_t)(ob + 16 * t + lr) * 512 + koff);
#pragma unroll
        for (int pt = 0; pt < 4; ++pt) {
            f16x8 B = *(const f16x8*)(cat + (size_t)(p0 + pt * 16 + lr) * 512 + koff);
#pragma unroll
            for (int t = 0; t < 4; ++t)
                acc[pt][t] = __builtin_amdgcn_mfma_f32_16x16x32_f16(A[t], B, acc[pt][t], 0, 0, 0);
        }
    }
#pragma unroll
    for (int pt = 0; pt < 4; ++pt) {
        int px = p0 + pt * 16 + lr;
        int b = px >> 11, n = px & 2047;
#pragma unroll
        for (int t = 0; t < 4; ++t) {
#pragma unroll
            for (int j = 0; j < 4; ++j) {
                int o = ob + 16 * t + 4 * lg + j;
                out[((size_t)(b * 512 + o)) * 2048 + n] = acc[pt][t][j];
            }
        }
    }
    __shared__ float lsum[4][64], lsq[4][64];
#pragma unroll
    for (int t = 0; t < 4; ++t)
#pragma unroll
        for (int j = 0; j < 4; ++j) {
            float s = acc[0][t][j] + acc[1][t][j] + acc[2][t][j] + acc[3][t][j];
            float q = acc[0][t][j] * acc[0][t][j] + acc[1][t][j] * acc[1][t][j]
                    + acc[2][t][j] * acc[2][t][j] + acc[3][t][j] * acc[3][t][j];
#pragma unroll
            for (int m2 = 1; m2 < 16; m2 <<= 1) { s += __shfl_xor(s, m2); q += __shfl_xor(q, m2); }
            if (lr == 0) { lsum[wid][16 * t + 4 * lg + j] = s; lsq[wid][16 * t + 4 * lg + j] = q; }
        }
    __syncthreads();
    if (tid < 64) {
        float S = lsum[0][tid] + lsum[1][tid] + lsum[2][tid] + lsum[3][tid];
        float Q = lsq[0][tid] + lsq[1][tid] + lsq[2][tid] + lsq[3][tid];
        atomicAdd(st + ob + tid, S);
        atomicAdd(st + 512 + ob + tid, Q);
    }
}

// ---------- per-channel stats over raw y [P][C] (layer 1 only) ----------
template<int C>
__global__ __launch_bounds__(256) void stats_pm_kernel(const f16* __restrict__ y,
                                                       float* __restrict__ st, int P) {
    const int c   = threadIdx.x & (C - 1);
    const int grp = threadIdx.x / C;
    const int GR  = 256 / C;
    const int CH  = P / gridDim.x;
    const int pend = blockIdx.x * CH + CH;
    float s = 0.f, q = 0.f;
    for (int p = blockIdx.x * CH + grp; p < pend; p += GR) {
        float v = (float)y[(size_t)p * C + c];
        s += v; q += v * v;
    }
    atomicAdd(st + c, s);
    atomicAdd(st + 512 + c, q);
}

// ---------- BN finalize ----------
__global__ void finalize_kernel(const float* __restrict__ st, const float* __restrict__ g,
                                const float* __restrict__ bb, float* __restrict__ scsh,
                                int C, float invM) {
    int c = threadIdx.x;
    if (c < C) {
        float mean = st[c] * invM;
        float var  = st[512 + c] * invM - mean * mean;
        float istd = rsqrtf(var + EPS_BN);
        float sc   = g[c] * istd;
        scsh[c]       = sc;
        scsh[512 + c] = bb[c] - mean * sc;
    }
}

// ---------- normalize in place ([P][C]) + per-point max -> cat slice ----------
template<int C>
__global__ __launch_bounds__(256) void norm_catmax_kernel(f16* __restrict__ y,
                                                          const float* __restrict__ scsh,
                                                          f16* __restrict__ cat, int coff) {
    const int c   = threadIdx.x & (C - 1);
    const int grp = threadIdx.x / C;
    const int GR  = 256 / C;
    const int r0  = blockIdx.x * 16;
    const float sc = scsh[c], sh = scsh[512 + c];
    for (int rl = grp; rl < 16; rl += GR) {
        int r = r0 + rl;
        f16* base = y + (size_t)r * KK * C + c;
        float mx = 0.f;
#pragma unroll
        for (int k = 0; k < KK; ++k) {
            float v = fmaxf(fmaf((float)base[(size_t)k * C], sc, sh), 0.f);
            base[(size_t)k * C] = (f16)v;
            mx = fmaxf(mx, v);
        }
        cat[(size_t)r * 512 + coff + c] = (f16)mx;
    }
}

// ---------- final normalize + ReLU on conv5 output in place ----------
__global__ __launch_bounds__(256) void norm5_kernel(float* __restrict__ out,
                                                    const float* __restrict__ scsh) {
    int o = blockIdx.y;
    int r = blockIdx.x * 256 + threadIdx.x;
    int b = r >> 11, n = r & 2047;
    float sc = scsh[o], sh = scsh[512 + o];
    size_t i = ((size_t)(b * 512 + o)) * 2048 + n;
    float v = fmaf(out[i], sc, sh);
    out[i] = v > 0.f ? v : 0.f;
}

extern "C" void kernel_launch(void* const* d_in, const int* in_sizes, int n_in,
                              void* d_out, int out_size, void* d_ws, size_t ws_size,
                              hipStream_t stream) {
    float* out = (float*)d_out;
    if (ws_size < WS_NEED) {
        marker_kernel<<<1, 64, 0, stream>>>(out, 1000.0f + (float)(ws_size >> 20));
        return;
    }

    const float* x  = (const float*)d_in[0];
    const float* W1 = (const float*)d_in[1];
    const float* g1 = (const float*)d_in[2];
    const float* b1 = (const float*)d_in[3];
    const float* W2 = (const float*)d_in[4];
    const float* g2 = (const float*)d_in[5];
    const float* b2 = (const float*)d_in[6];
    const float* W3 = (const float*)d_in[7];
    const float* g3 = (const float*)d_in[8];
    const float* b3 = (const float*)d_in[9];
    const float* W4 = (const float*)d_in[10];
    const float* g4 = (const float*)d_in[11];
    const float* b4 = (const float*)d_in[12];
    const float* W5 = (const float*)d_in[13];
    const float* g5 = (const float*)d_in[14];
    const float* b5 = (const float*)d_in[15];

    char*  ws    = (char*)d_ws;
    int*   idx   = (int*)(ws + OFF_IDX);
    float* wt1   = (float*)(ws + OFF_WT1);
    f16*   wh2   = (f16*)(ws + OFF_WH2);
    f16*   wh3   = (f16*)(ws + OFF_WH3);
    f16*   wh4   = (f16*)(ws + OFF_WH4);
    f16*   wh5   = (f16*)(ws + OFF_WH5);
    float* stats = (float*)(ws + OFF_ST);
    float* scsh  = (float*)(ws + OFF_SS);
    f16*   cat   = (f16*)(ws + OFF_CAT);
    f16*   y1    = (f16*)(ws + OFF_Y1);
    f16*   y2    = (f16*)(ws + OFF_Y2);
    f16*   y3    = (f16*)(ws + OFF_Y3);
    f16*   mx4   = (f16*)(ws + OFF_Y2);                          // y2 dead at L4
    f16*   mn4   = (f16*)(ws + OFF_Y2 + (size_t)BNP * 256 * 2);

    hipMemsetAsync(stats, 0, 5 * 1024 * sizeof(float), stream);

    prep_weights<<<1024, 256, 0, stream>>>(W1, W2, W3, W4, W5, wt1, wh2, wh3, wh4, wh5);
    knn_kernel<<<4096, 256, 0, stream>>>(x, idx);

    const float invM  = 1.0f / (float)PT;
    const float invM5 = 1.0f / (float)BNP;

    // L1: 6 -> 64
    conv1_kernel<<<PT / 256, 256, 0, stream>>>(x, idx, wt1, y1);
    stats_pm_kernel<64><<<256, 256, 0, stream>>>(y1, stats + 0, PT);
    finalize_kernel<<<1, 512, 0, stream>>>(stats + 0, g1, b1, scsh + 0, 64, invM);
    norm_catmax_kernel<64><<<BNP / 16, 256, 0, stream>>>(y1, scsh + 0, cat, 0);

    // L2: 64 -> 64 (stats fused)
    conv_mfma_kernel<64, 64><<<dim3(PT / 256, 1), 256, 0, stream>>>(y1, wh2, y2, stats + 1024);
    finalize_kernel<<<1, 512, 0, stream>>>(stats + 1024, g2, b2, scsh + 1024, 64, invM);
    norm_catmax_kernel<64><<<BNP / 16, 256, 0, stream>>>(y2, scsh + 1024, cat, 64);

    // L3: 64 -> 128 (stats fused; clobbers dead y1)
    conv_mfma_kernel<64, 128><<<dim3(PT / 256, 2), 256, 0, stream>>>(y2, wh3, y3, stats + 2048);
    finalize_kernel<<<1, 512, 0, stream>>>(stats + 2048, g3, b3, scsh + 2048, 128, invM);
    norm_catmax_kernel<128><<<BNP / 16, 256, 0, stream>>>(y3, scsh + 2048, cat, 128);

    // L4: 128 -> 256, ONE GEMM: stats + raw max/min over k; then BN via monotone commute
    conv4_fused_mfma<<<PT / 320, 320, 0, stream>>>(y3, wh4, stats + 3072, mx4, mn4);
    finalize_kernel<<<1, 512, 0, stream>>>(stats + 3072, g4, b4, scsh + 3072, 256, invM);
    cat4_kernel<<<BNP, 256, 0, stream>>>(mx4, mn4, scsh + 3072, cat);

    // L5: 512 -> 512 on cat -> d_out raw (stats fused)
    conv5_mfma<<<dim3(BNP / 256, 8), 256, 0, stream>>>(cat, wh5, out, stats + 4096);
    finalize_kernel<<<1, 512, 0, stream>>>(stats + 4096, g5, b5, scsh + 4096, 512, invM5);
    norm5_kernel<<<dim3(BNP / 256, 512), 256, 0, stream>>>(out, scsh + 4096);
}

// Round 9
// 574.814 us; speedup vs baseline: 3.2186x; 1.1205x over previous
//
#include <hip/hip_runtime.h>
#include <hip/hip_bf16.h>

typedef _Float16 f16;
typedef _Float16 f16x8 __attribute__((ext_vector_type(8)));
typedef _Float16 f16x4 __attribute__((ext_vector_type(4)));
typedef float    f32x4 __attribute__((ext_vector_type(4)));
typedef unsigned long long u64;

constexpr int NB  = 8;
constexpr int NPT = 2048;
constexpr int KK  = 20;
constexpr int PT  = NB * NPT * KK;   // 327680 pixels, layers 1-4
constexpr int BNP = NB * NPT;        // 16384 points
constexpr float EPS_BN = 1e-5f;

// ---------- workspace layout (bytes), total ~144.6 MB ----------
constexpr size_t OFF_IDX = 0;
constexpr size_t OFF_WT1 = OFF_IDX + (size_t)BNP * KK * 4;
constexpr size_t OFF_WH2 = OFF_WT1 + 384 * 4;
constexpr size_t OFF_WH3 = OFF_WH2 + 4096 * 2;
constexpr size_t OFF_WH4 = OFF_WH3 + 8192 * 2;
constexpr size_t OFF_WH5 = OFF_WH4 + 32768 * 2;
constexpr size_t OFF_ST  = OFF_WH5 + 262144 * 2;
constexpr size_t OFF_SS  = OFF_ST + 5 * 1024 * 4;
constexpr size_t OFF_CAT = OFF_SS + 5 * 1024 * 4;                // f16 [BNP][512]
constexpr size_t OFF_Y3  = OFF_CAT + (size_t)BNP * 512 * 2;      // f16 [PT][128]
constexpr size_t OFF_Y1  = OFF_Y3 + (size_t)PT * 64 * 2;         // aliases upper half of y3
constexpr size_t OFF_Y2  = OFF_Y3 + (size_t)PT * 128 * 2;        // f16 [PT][64]; at L4: mx4|mn4
constexpr size_t WS_NEED = OFF_Y2 + (size_t)PT * 64 * 2;         // 144,573,952 B

// ---------- diagnostic ----------
__global__ void marker_kernel(float* __restrict__ out, float v) {
    if (threadIdx.x == 0 && blockIdx.x == 0) out[0] = v;
}

// ---------- weight prep ----------
__global__ __launch_bounds__(256) void prep_weights(
        const float* __restrict__ W1, const float* __restrict__ W2,
        const float* __restrict__ W3, const float* __restrict__ W4,
        const float* __restrict__ W5,
        float* __restrict__ wt1, f16* __restrict__ wh2, f16* __restrict__ wh3,
        f16* __restrict__ wh4, f16* __restrict__ wh5) {
    int i = blockIdx.x * 256 + threadIdx.x;
    if (i < 384)    { int o = i / 6, c = i - o * 6; wt1[c * 64 + o] = W1[i]; }
    if (i < 4096)   wh2[i] = (f16)W2[i];
    if (i < 8192)   wh3[i] = (f16)W3[i];
    if (i < 32768)  wh4[i] = (f16)W4[i];
    if (i < 262144) wh5[i] = (f16)W5[i];
}

// ---------- kNN v5: u64-key queues + scalar bisection selection + f64 refine ----------
__device__ __forceinline__ float distf(const float* __restrict__ xb, int m,
                                       float xn0, float xn1, float xn2, float sqn) {
    float xm0 = xb[m], xm1 = xb[NPT + m], xm2 = xb[2 * NPT + m];
    float dot = xn0 * xm0 + xn1 * xm1 + xn2 * xm2;
    float sqm = xm0 * xm0 + xm1 * xm1 + xm2 * xm2;
    return 2.f * dot - sqn - sqm;
}
__device__ __forceinline__ u64 mkkey(float d, int m) {
    unsigned u = __float_as_uint(d);
    u = (u & 0x80000000u) ? ~u : (u | 0x80000000u);      // monotone f32 -> u32
    return ((u64)u << 32) | (unsigned)(2047 - m);        // (value desc, m asc) as u64 max
}
__device__ __forceinline__ int key2m(u64 k) { return 2047 - (int)(k & 0xFFFFFFFFull); }

__device__ __forceinline__ void qins(u64 k, u64& q0, u64& q1, u64& q2, u64& q3, u64& spill) {
    bool c0 = k > q0, c1 = k > q1, c2 = k > q2, c3 = k > q3;
    u64 drop = c3 ? q3 : k;
    spill = spill > drop ? spill : drop;
    q3 = c2 ? q2 : (c3 ? k : q3);
    q2 = c1 ? q1 : (c2 ? k : q2);
    q1 = c0 ? q0 : (c1 ? k : q1);
    q0 = c0 ? k  : q0;
}

__global__ __launch_bounds__(256) void knn_kernel(const float* __restrict__ x,
                                                  int* __restrict__ idxo) {
    const int lane = threadIdx.x & 63;
    const int wid  = threadIdx.x >> 6;
    const int r    = blockIdx.x * 4 + wid;
    const int b    = r >> 11;
    const int n    = r & 2047;
    const float* xb = x + b * (3 * NPT);

    const float xn0 = xb[n], xn1 = xb[NPT + n], xn2 = xb[2 * NPT + n];
    const float sqn = xn0 * xn0 + xn1 * xn1 + xn2 * xn2;

    u64 q0 = 0, q1 = 0, q2 = 0, q3 = 0, spill = 0;
#pragma unroll
    for (int i = 0; i < 32; ++i) {
        int m = i * 64 + lane;                           // coalesced
        qins(mkkey(distf(xb, m, xn0, xn1, xn2, sqn), m), q0, q1, q2, q3, spill);
    }

    __shared__ int cand[4][32];
    int C;

    // bisection: T = max u32 with count(value >= T) >= 26, counted over queues
    unsigned lo = 0u, hi = 0xFFFFFFFFu;
#pragma unroll 1
    for (int it = 0; it < 32 && lo < hi; ++it) {
        unsigned span = hi - lo;
        unsigned mid  = lo + (span >> 1) + (span & 1);   // ceil-avg, no overflow
        u64 M = (u64)mid << 32;
        int cnt = __popcll(__ballot(q0 >= M)) + __popcll(__ballot(q1 >= M))
                + __popcll(__ballot(q2 >= M)) + __popcll(__ballot(q3 >= M));
        if (cnt >= 26) lo = mid; else hi = mid - 1;
    }
    const u64 T64 = (u64)lo << 32;

    u64 b0 = __ballot(q0 >= T64), b1 = __ballot(q1 >= T64);
    u64 b2 = __ballot(q2 >= T64), b3 = __ballot(q3 >= T64);
    int n0 = __popcll(b0), n1 = __popcll(b1), n2 = __popcll(b2), n3 = __popcll(b3);
    C = n0 + n1 + n2 + n3;
    bool conflict = (__ballot(spill >= T64) != 0ull) || (C > 32);

    if (!conflict) {
        // compact selected m's into cand[wid][0..C)
        u64 ltm = (1ull << lane) - 1ull;
        if (q0 >= T64) cand[wid][__popcll(b0 & ltm)] = key2m(q0);
        if (q1 >= T64) cand[wid][n0 + __popcll(b1 & ltm)] = key2m(q1);
        if (q2 >= T64) cand[wid][n0 + n1 + __popcll(b2 & ltm)] = key2m(q2);
        if (q3 >= T64) cand[wid][n0 + n1 + n2 + __popcll(b3 & ltm)] = key2m(q3);
    } else {
        // rare fallback: verified v4-style 26-round extraction with rescue
        C = 26;
#pragma unroll 1
        for (int t = 0; t < 26; ++t) {
            u64 v = q0;
#pragma unroll
            for (int s = 1; s < 64; s <<= 1) {
                u64 ov = __shfl_xor(v, s);
                if (ov > v) v = ov;
            }
            if (lane == 0) cand[wid][t] = key2m(v);
            if (q0 == v) {                               // unique owner pops
                q0 = q1; q1 = q2; q2 = q3; q3 = 0;
                if (!(q0 > spill)) {                     // rescue rebuild
                    q0 = q1 = q2 = q3 = 0; spill = 0;
                    for (int ii = 0; ii < 32; ++ii) {
                        int mr = ii * 64 + lane;
                        u64 kr = mkkey(distf(xb, mr, xn0, xn1, xn2, sqn), mr);
                        if (kr < v) qins(kr, q0, q1, q2, q3, spill);
                    }
                }
            }
        }
    }
    __syncthreads();

    // exact f64 refine (expression identical to the verified f64 kernel)
    int mm = (lane < C) ? cand[wid][lane] : 0;
    const double dxn0 = (double)xn0, dxn1 = (double)xn1, dxn2 = (double)xn2;
    const double dsqn = dxn0 * dxn0 + dxn1 * dxn1 + dxn2 * dxn2;
    double xm0 = (double)xb[mm], xm1 = (double)xb[NPT + mm], xm2 = (double)xb[2 * NPT + mm];
    double ddot = dxn0 * xm0 + dxn1 * xm1 + dxn2 * xm2;
    double dsqm = xm0 * xm0 + xm1 * xm1 + xm2 * xm2;
    double dd   = 2.0 * ddot - dsqn - dsqm;

    int rank = 0;
#pragma unroll 1
    for (int s = 0; s < C; ++s) {
        double ds = __shfl(dd, s);
        int    ms = __shfl(mm, s);
        if (ds > dd || (ds == dd && ms < mm)) ++rank;
    }
    if (lane < C && rank < KK) idxo[r * KK + rank] = mm;
}

// ---------- conv1: edge features -> y1 [P][64] f16 (raw) ----------
__global__ __launch_bounds__(256) void conv1_kernel(const float* __restrict__ x,
                                                    const int* __restrict__ idx,
                                                    const float* __restrict__ Wt,
                                                    f16* __restrict__ y) {
    int p = blockIdx.x * 256 + threadIdx.x;
    int t = p / KK;
    int n = t & 2047;
    int b = t >> 11;
    int m = idx[p];
    const float* xb = x + b * (3 * NPT);
    float f3 = xb[n], f4 = xb[NPT + n], f5 = xb[2 * NPT + n];
    float f0 = xb[m] - f3, f1 = xb[NPT + m] - f4, f2 = xb[2 * NPT + m] - f5;
    float fv[6] = { f0, f1, f2, f3, f4, f5 };

    float acc[64];
#pragma unroll
    for (int o = 0; o < 64; ++o) acc[o] = 0.f;
#pragma unroll
    for (int c = 0; c < 6; ++c) {
        float hv = fv[c];
#pragma unroll
        for (int o = 0; o < 64; ++o) acc[o] = fmaf(Wt[c * 64 + o], hv, acc[o]);
    }
    f16* yp = y + (size_t)p * 64;
#pragma unroll
    for (int o = 0; o < 64; ++o) yp[o] = (f16)acc[o];
}

// ---------- MFMA GEMM, input-BN applied on load, fused output stats ----------
// OBW: out-blocks per block handled by wave split (waves share px, differ in ob).
template<int CIN, int OBW>
__global__ __launch_bounds__(256) void conv_mfma_kernel(const f16* __restrict__ h,
                                                        const f16* __restrict__ W,
                                                        const float* __restrict__ scshIn,
                                                        f16* __restrict__ y,
                                                        float* __restrict__ st) {
    constexpr int COUT = OBW * 64;
    const int tid = threadIdx.x, lane = tid & 63, wid = tid >> 6;
    const int lr = lane & 15, lg = lane >> 4;
    const int p0 = blockIdx.x * (256 / OBW) + (wid / OBW) * 64;
    const int ob = (wid & (OBW - 1)) * 64;

    // load + normalize(ReLU(BN)) B fragments once
    f16x8 Bn[CIN / 32][4];
#pragma unroll
    for (int kt = 0; kt < CIN / 32; ++kt) {
        const int koff = kt * 32 + lg * 8;
        const float4 s0 = *(const float4*)(scshIn + koff);
        const float4 s1 = *(const float4*)(scshIn + koff + 4);
        const float4 h0 = *(const float4*)(scshIn + 512 + koff);
        const float4 h1 = *(const float4*)(scshIn + 512 + koff + 4);
        const float scr[8] = { s0.x, s0.y, s0.z, s0.w, s1.x, s1.y, s1.z, s1.w };
        const float shr[8] = { h0.x, h0.y, h0.z, h0.w, h1.x, h1.y, h1.z, h1.w };
#pragma unroll
        for (int pt = 0; pt < 4; ++pt) {
            f16x8 raw = *(const f16x8*)(h + (size_t)(p0 + pt * 16 + lr) * CIN + koff);
            f16x8 Bv;
#pragma unroll
            for (int e = 0; e < 8; ++e)
                Bv[e] = (f16)fmaxf(fmaf((float)raw[e], scr[e], shr[e]), 0.f);
            Bn[kt][pt] = Bv;
        }
    }

    f32x4 acc[4][4];
#pragma unroll
    for (int pt = 0; pt < 4; ++pt)
#pragma unroll
        for (int t = 0; t < 4; ++t) acc[pt][t] = (f32x4){0.f, 0.f, 0.f, 0.f};

#pragma unroll
    for (int kt = 0; kt < CIN / 32; ++kt) {
        const int koff = kt * 32 + lg * 8;
        f16x8 A[4];
#pragma unroll
        for (int t = 0; t < 4; ++t)
            A[t] = *(const f16x8*)(W + (size_t)(ob + 16 * t + lr) * CIN + koff);
#pragma unroll
        for (int pt = 0; pt < 4; ++pt)
#pragma unroll
            for (int t = 0; t < 4; ++t)
                acc[pt][t] = __builtin_amdgcn_mfma_f32_16x16x32_f16(A[t], Bn[kt][pt], acc[pt][t], 0, 0, 0);
    }
#pragma unroll
    for (int pt = 0; pt < 4; ++pt) {
        int px = p0 + pt * 16 + lr;
#pragma unroll
        for (int t = 0; t < 4; ++t) {
            f16x4 v;
            v[0] = (f16)acc[pt][t][0]; v[1] = (f16)acc[pt][t][1];
            v[2] = (f16)acc[pt][t][2]; v[3] = (f16)acc[pt][t][3];
            *(f16x4*)(y + (size_t)px * COUT + ob + 16 * t + 4 * lg) = v;
        }
    }
    __shared__ float lsum[4][64], lsq[4][64];
#pragma unroll
    for (int t = 0; t < 4; ++t)
#pragma unroll
        for (int j = 0; j < 4; ++j) {
            float s = acc[0][t][j] + acc[1][t][j] + acc[2][t][j] + acc[3][t][j];
            float q = acc[0][t][j] * acc[0][t][j] + acc[1][t][j] * acc[1][t][j]
                    + acc[2][t][j] * acc[2][t][j] + acc[3][t][j] * acc[3][t][j];
#pragma unroll
            for (int m2 = 1; m2 < 16; m2 <<= 1) { s += __shfl_xor(s, m2); q += __shfl_xor(q, m2); }
            if (lr == 0) { lsum[wid][16 * t + 4 * lg + j] = s; lsq[wid][16 * t + 4 * lg + j] = q; }
        }
    __syncthreads();
    if (tid < COUT) {
        int obIdx = tid >> 6, c = tid & 63;
        float S = 0.f, Q = 0.f;
#pragma unroll
        for (int w = obIdx; w < 4; w += OBW) { S += lsum[w][c]; Q += lsq[w][c]; }
        atomicAdd(st + tid, S);
        atomicAdd(st + 512 + tid, Q);
    }
}

// ---------- conv4 fused: input-BN on load, single GEMM -> stats + raw max/min over k ----------
__global__ __launch_bounds__(320) void conv4_fused_mfma(const f16* __restrict__ h,
                                                        const f16* __restrict__ W,
                                                        const float* __restrict__ scshIn,
                                                        float* __restrict__ st,
                                                        f16* __restrict__ mx4,
                                                        f16* __restrict__ mn4) {
    const int tid = threadIdx.x, lane = tid & 63, wid = tid >> 6;   // 5 waves
    const int lr = lane & 15, lg = lane >> 4;
    const int p0 = blockIdx.x * 320 + wid * 64;
    const int r0 = blockIdx.x * 16;                  // 320 px = 16 points

    f16x8 Bf[4][4];                                  // h read ONCE, normalized
#pragma unroll
    for (int kt = 0; kt < 4; ++kt) {
        const int koff = kt * 32 + lg * 8;
        const float4 s0 = *(const float4*)(scshIn + koff);
        const float4 s1 = *(const float4*)(scshIn + koff + 4);
        const float4 h0 = *(const float4*)(scshIn + 512 + koff);
        const float4 h1 = *(const float4*)(scshIn + 512 + koff + 4);
        const float scr[8] = { s0.x, s0.y, s0.z, s0.w, s1.x, s1.y, s1.z, s1.w };
        const float shr[8] = { h0.x, h0.y, h0.z, h0.w, h1.x, h1.y, h1.z, h1.w };
#pragma unroll
        for (int pt = 0; pt < 4; ++pt) {
            f16x8 raw = *(const f16x8*)(h + (size_t)(p0 + pt * 16 + lr) * 128 + koff);
            f16x8 Bv;
#pragma unroll
            for (int e = 0; e < 8; ++e)
                Bv[e] = (f16)fmaxf(fmaf((float)raw[e], scr[e], shr[e]), 0.f);
            Bf[kt][pt] = Bv;
        }
    }

    __shared__ f16   sb[320][68];
    __shared__ float lsum[5][256], lsq[5][256];

#pragma unroll 1
    for (int ob4 = 0; ob4 < 4; ++ob4) {
        const int ob = ob4 * 64;
        f32x4 acc[4][4];
#pragma unroll
        for (int pt = 0; pt < 4; ++pt)
#pragma unroll
            for (int t = 0; t < 4; ++t) acc[pt][t] = (f32x4){0.f, 0.f, 0.f, 0.f};
#pragma unroll
        for (int kt = 0; kt < 4; ++kt) {
            const int koff = kt * 32 + lg * 8;
            f16x8 A[4];
#pragma unroll
            for (int t = 0; t < 4; ++t)
                A[t] = *(const f16x8*)(W + (size_t)(ob + 16 * t + lr) * 128 + koff);
#pragma unroll
            for (int pt = 0; pt < 4; ++pt)
#pragma unroll
                for (int t = 0; t < 4; ++t)
                    acc[pt][t] = __builtin_amdgcn_mfma_f32_16x16x32_f16(A[t], Bf[kt][pt], acc[pt][t], 0, 0, 0);
        }
        // stats
#pragma unroll
        for (int t = 0; t < 4; ++t)
#pragma unroll
            for (int j = 0; j < 4; ++j) {
                float s = acc[0][t][j] + acc[1][t][j] + acc[2][t][j] + acc[3][t][j];
                float q = acc[0][t][j] * acc[0][t][j] + acc[1][t][j] * acc[1][t][j]
                        + acc[2][t][j] * acc[2][t][j] + acc[3][t][j] * acc[3][t][j];
#pragma unroll
                for (int m2 = 1; m2 < 16; m2 <<= 1) { s += __shfl_xor(s, m2); q += __shfl_xor(q, m2); }
                if (lr == 0) { lsum[wid][ob + 16 * t + 4 * lg + j] = s; lsq[wid][ob + 16 * t + 4 * lg + j] = q; }
            }
        // stage raw y4, reduce max AND min over k
#pragma unroll
        for (int t = 0; t < 4; ++t) {
            int och = 16 * t + 4 * lg;
#pragma unroll
            for (int pt = 0; pt < 4; ++pt) {
                int pl = wid * 64 + pt * 16 + lr;
                sb[pl][och + 0] = (f16)acc[pt][t][0];
                sb[pl][och + 1] = (f16)acc[pt][t][1];
                sb[pl][och + 2] = (f16)acc[pt][t][2];
                sb[pl][och + 3] = (f16)acc[pt][t][3];
            }
        }
        __syncthreads();
        if (tid < 256) {
            int rl = tid >> 4, cq = tid & 15;
#pragma unroll
            for (int cb = 0; cb < 4; ++cb) {
                int ch = cb * 16 + cq;
                float mx = -3.3e38f, mn = 3.3e38f;
#pragma unroll
                for (int k = 0; k < KK; ++k) {
                    float v = (float)sb[rl * KK + k][ch];
                    mx = fmaxf(mx, v); mn = fminf(mn, v);
                }
                mx4[(size_t)(r0 + rl) * 256 + ob + ch] = (f16)mx;
                mn4[(size_t)(r0 + rl) * 256 + ob + ch] = (f16)mn;
            }
        }
        __syncthreads();
    }
    if (tid < 256) {
        float S = lsum[0][tid] + lsum[1][tid] + lsum[2][tid] + lsum[3][tid] + lsum[4][tid];
        float Q = lsq[0][tid] + lsq[1][tid] + lsq[2][tid] + lsq[3][tid] + lsq[4][tid];
        atomicAdd(st + tid, S);
        atomicAdd(st + 512 + tid, Q);
    }
}

// ---------- conv4 epilogue: BN+ReLU on max/min (monotone commute) -> cat ----------
__global__ __launch_bounds__(256) void cat4_kernel(const f16* __restrict__ mx4,
                                                   const f16* __restrict__ mn4,
                                                   const float* __restrict__ scsh,
                                                   f16* __restrict__ cat) {
    int i = blockIdx.x * 256 + threadIdx.x;
    int r = i >> 8, ch = i & 255;
    float sc = scsh[ch], sh = scsh[512 + ch];
    float v  = (sc > 0.f) ? (float)mx4[i] : (float)mn4[i];
    cat[(size_t)r * 512 + 256 + ch] = (f16)fmaxf(fmaf(v, sc, sh), 0.f);
}

// ---------- conv5: waves share px, differ in ob (cat read 2x not 8x) ----------
__global__ __launch_bounds__(256) void conv5_mfma(const f16* __restrict__ cat,
                                                  const f16* __restrict__ W,
                                                  float* __restrict__ out,
                                                  float* __restrict__ st) {
    const int tid = threadIdx.x;
    const int lane = tid & 63, wid = tid >> 6;
    const int lr = lane & 15, lg = lane >> 4;
    const int p0 = blockIdx.x * 64;                  // 4 waves share these 64 px
    const int ob = blockIdx.y * 256 + wid * 64;

    f32x4 acc[4][4];
#pragma unroll
    for (int pt = 0; pt < 4; ++pt)
#pragma unroll
        for (int t = 0; t < 4; ++t) acc[pt][t] = (f32x4){0.f, 0.f, 0.f, 0.f};

#pragma unroll
    for (int kt = 0; kt < 16; ++kt) {
        const int koff = kt * 32 + lg * 8;
        f16x8 A[4];
#pragma unroll
        for (int t = 0; t < 4; ++t)
            A[t] = *(const f16x8*)(W + (size_t)(ob + 16 * t + lr) * 512 + koff);
#pragma unroll
        for (int pt = 0; pt < 4; ++pt) {
            f16x8 B = *(const f16x8*)(cat + (size_t)(p0 + pt * 16 + lr) * 512 + koff);
#pragma unroll
            for (int t = 0; t < 4; ++t)
                acc[pt][t] = __builtin_amdgcn_mfma_f32_16x16x32_f16(A[t], B, acc[pt][t], 0, 0, 0);
        }
    }
#pragma unroll
    for (int pt = 0; pt < 4; ++pt) {
        int px = p0 + pt * 16 + lr;
        int b = px >> 11, n = px & 2047;
#pragma unroll
        for (int t = 0; t < 4; ++t) {
#pragma unroll
            for (int j = 0; j < 4; ++j) {
                int o = ob + 16 * t + 4 * lg + j;
                out[((size_t)(b * 512 + o)) * 2048 + n] = acc[pt][t][j];
            }
        }
    }
    __shared__ float lsum[4][64], lsq[4][64];
#pragma unroll
    for (int t = 0; t < 4; ++t)
#pragma unroll
        for (int j = 0; j < 4; ++j) {
            float s = acc[0][t][j] + acc[1][t][j] + acc[2][t][j] + acc[3][t][j];
            float q = acc[0][t][j] * acc[0][t][j] + acc[1][t][j] * acc[1][t][j]
                    + acc[2][t][j] * acc[2][t][j] + acc[3][t][j] * acc[3][t][j];
#pragma unroll
            for (int m2 = 1; m2 < 16; m2 <<= 1) { s += __shfl_xor(s, m2); q += __shfl_xor(q, m2); }
            if (lr == 0) { lsum[wid][16 * t + 4 * lg + j] = s; lsq[wid][16 * t + 4 * lg + j] = q; }
        }
    __syncthreads();
    if (tid < 256) {
        int w = tid >> 6, c = tid & 63;
        atomicAdd(st + blockIdx.y * 256 + tid, lsum[w][c]);
        atomicAdd(st + 512 + blockIdx.y * 256 + tid, lsq[w][c]);
    }
}

// ---------- per-channel stats over raw y [P][C] (layer 1 only) ----------
template<int C>
__global__ __launch_bounds__(256) void stats_pm_kernel(const f16* __restrict__ y,
                                                       float* __restrict__ st, int P) {
    const int c   = threadIdx.x & (C - 1);
    const int grp = threadIdx.x / C;
    const int GR  = 256 / C;
    const int CH  = P / gridDim.x;
    const int pend = blockIdx.x * CH + CH;
    float s = 0.f, q = 0.f;
    for (int p = blockIdx.x * CH + grp; p < pend; p += GR) {
        float v = (float)y[(size_t)p * C + c];
        s += v; q += v * v;
    }
    atomicAdd(st + c, s);
    atomicAdd(st + 512 + c, q);
}

// ---------- BN finalize ----------
__global__ void finalize_kernel(const float* __restrict__ st, const float* __restrict__ g,
                                const float* __restrict__ bb, float* __restrict__ scsh,
                                int C, float invM) {
    int c = threadIdx.x;
    if (c < C) {
        float mean = st[c] * invM;
        float var  = st[512 + c] * invM - mean * mean;
        float istd = rsqrtf(var + EPS_BN);
        float sc   = g[c] * istd;
        scsh[c]       = sc;
        scsh[512 + c] = bb[c] - mean * sc;
    }
}

// ---------- read-only catmax: BN+ReLU on the fly, max over k -> cat slice ----------
template<int C>
__global__ __launch_bounds__(256) void catmax_raw(const f16* __restrict__ y,
                                                  const float* __restrict__ scsh,
                                                  f16* __restrict__ cat, int coff) {
    const int c   = threadIdx.x & (C - 1);
    const int grp = threadIdx.x / C;
    const int GR  = 256 / C;
    const int r0  = blockIdx.x * 16;
    const float sc = scsh[c], sh = scsh[512 + c];
    for (int rl = grp; rl < 16; rl += GR) {
        int r = r0 + rl;
        const f16* base = y + (size_t)r * KK * C + c;
        float mx = -3.3e38f;
#pragma unroll
        for (int k = 0; k < KK; ++k)
            mx = fmaxf(mx, fmaf((float)base[(size_t)k * C], sc, sh));
        cat[(size_t)r * 512 + coff + c] = (f16)fmaxf(mx, 0.f);
    }
}

// ---------- final normalize + ReLU on conv5 output in place ----------
__global__ __launch_bounds__(256) void norm5_kernel(float* __restrict__ out,
                                                    const float* __restrict__ scsh) {
    int o = blockIdx.y;
    int r = blockIdx.x * 256 + threadIdx.x;
    int b = r >> 11, n = r & 2047;
    float sc = scsh[o], sh = scsh[512 + o];
    size_t i = ((size_t)(b * 512 + o)) * 2048 + n;
    float v = fmaf(out[i], sc, sh);
    out[i] = v > 0.f ? v : 0.f;
}

extern "C" void kernel_launch(void* const* d_in, const int* in_sizes, int n_in,
                              void* d_out, int out_size, void* d_ws, size_t ws_size,
                              hipStream_t stream) {
    float* out = (float*)d_out;
    if (ws_size < WS_NEED) {
        marker_kernel<<<1, 64, 0, stream>>>(out, 1000.0f + (float)(ws_size >> 20));
        return;
    }

    const float* x  = (const float*)d_in[0];
    const float* W1 = (const float*)d_in[1];
    const float* g1 = (const float*)d_in[2];
    const float* b1 = (const float*)d_in[3];
    const float* W2 = (const float*)d_in[4];
    const float* g2 = (const float*)d_in[5];
    const float* b2 = (const float*)d_in[6];
    const float* W3 = (const float*)d_in[7];
    const float* g3 = (const float*)d_in[8];
    const float* b3 = (const float*)d_in[9];
    const float* W4 = (const float*)d_in[10];
    const float* g4 = (const float*)d_in[11];
    const float* b4 = (const float*)d_in[12];
    const float* W5 = (const float*)d_in[13];
    const float* g5 = (const float*)d_in[14];
    const float* b5 = (const float*)d_in[15];

    char*  ws    = (char*)d_ws;
    int*   idx   = (int*)(ws + OFF_IDX);
    float* wt1   = (float*)(ws + OFF_WT1);
    f16*   wh2   = (f16*)(ws + OFF_WH2);
    f16*   wh3   = (f16*)(ws + OFF_WH3);
    f16*   wh4   = (f16*)(ws + OFF_WH4);
    f16*   wh5   = (f16*)(ws + OFF_WH5);
    float* stats = (float*)(ws + OFF_ST);
    float* scsh  = (float*)(ws + OFF_SS);
    f16*   cat   = (f16*)(ws + OFF_CAT);
    f16*   y1    = (f16*)(ws + OFF_Y1);
    f16*   y2    = (f16*)(ws + OFF_Y2);
    f16*   y3    = (f16*)(ws + OFF_Y3);
    f16*   mx4   = (f16*)(ws + OFF_Y2);                          // y2 dead at L4
    f16*   mn4   = (f16*)(ws + OFF_Y2 + (size_t)BNP * 256 * 2);

    hipMemsetAsync(stats, 0, 5 * 1024 * sizeof(float), stream);

    prep_weights<<<1024, 256, 0, stream>>>(W1, W2, W3, W4, W5, wt1, wh2, wh3, wh4, wh5);
    knn_kernel<<<4096, 256, 0, stream>>>(x, idx);

    const float invM  = 1.0f / (float)PT;
    const float invM5 = 1.0f / (float)BNP;

    // L1: 6 -> 64 (raw y1)
    conv1_kernel<<<PT / 256, 256, 0, stream>>>(x, idx, wt1, y1);
    stats_pm_kernel<64><<<256, 256, 0, stream>>>(y1, stats + 0, PT);
    finalize_kernel<<<1, 512, 0, stream>>>(stats + 0, g1, b1, scsh + 0, 64, invM);
    catmax_raw<64><<<BNP / 16, 256, 0, stream>>>(y1, scsh + 0, cat, 0);

    // L2: 64 -> 64 (BN1 applied on load; stats fused)
    conv_mfma_kernel<64, 1><<<PT / 256, 256, 0, stream>>>(y1, wh2, scsh + 0, y2, stats + 1024);
    finalize_kernel<<<1, 512, 0, stream>>>(stats + 1024, g2, b2, scsh + 1024, 64, invM);
    catmax_raw<64><<<BNP / 16, 256, 0, stream>>>(y2, scsh + 1024, cat, 64);

    // L3: 64 -> 128 (BN2 on load; OBW=2: y2 fetched once; clobbers dead y1)
    conv_mfma_kernel<64, 2><<<PT / 128, 256, 0, stream>>>(y2, wh3, scsh + 1024, y3, stats + 2048);
    finalize_kernel<<<1, 512, 0, stream>>>(stats + 2048, g3, b3, scsh + 2048, 128, invM);
    catmax_raw<128><<<BNP / 16, 256, 0, stream>>>(y3, scsh + 2048, cat, 128);

    // L4: 128 -> 256, BN3 on load, ONE GEMM: stats + raw max/min; BN via monotone commute
    conv4_fused_mfma<<<PT / 320, 320, 0, stream>>>(y3, wh4, scsh + 2048, stats + 3072, mx4, mn4);
    finalize_kernel<<<1, 512, 0, stream>>>(stats + 3072, g4, b4, scsh + 3072, 256, invM);
    cat4_kernel<<<BNP, 256, 0, stream>>>(mx4, mn4, scsh + 3072, cat);

    // L5: 512 -> 512 on cat -> d_out raw (stats fused)
    conv5_mfma<<<dim3(BNP / 64, 2), 256, 0, stream>>>(cat, wh5, out, stats + 4096);
    finalize_kernel<<<1, 512, 0, stream>>>(stats + 4096, g5, b5, scsh + 4096, 512, invM5);
    norm5_kernel<<<dim3(BNP / 256, 512), 256, 0, stream>>>(out, scsh + 4096);
}